// Round 2
// baseline (11865.636 us; speedup 1.0000x reference)
//
#include <hip/hip_runtime.h>
#include <math.h>

#define Bn   32
#define Sn   256
#define En   512
#define Hn   512
#define Wn   512
#define ENCn 1024
#define G4   2048
#define KTOT 1536

// ---------------- workspace layout (float offsets) ----------------
#define OFF_BSUM  0L            // [32][256][512]  4194304
#define OFF_U3    4194304L      // [32][256][512]  4194304
#define OFF_PE    8388608L      // [32][257][512]  4210688
#define OFF_WB    12599296L     // [32cb][256kq][64][4] 2097152  (Wx|Wh repack, K=1024)
#define OFF_W4B   14696448L     // [8cb][128kq][64][4]   262144
#define OFF_GATES 14958592L     // [32][2048]      65536
#define OFF_H     15024128L     // [32][512]       16384
#define OFF_C     15040512L     // [32][512]       16384
#define OFF_STATE 15056896L     // ints: bond[32], last[32], nact@64, bar@65

// ---------------- init ----------------
__global__ void init_kernel(const float* __restrict__ hn0, float* __restrict__ h,
                            float* __restrict__ c, int* __restrict__ state)
{
    int i = blockIdx.x * blockDim.x + threadIdx.x;
    if (i < Bn * Hn) { h[i] = 0.0f; c[i] = hn0[i]; }
    if (i < Bn) { state[i] = 0; state[32 + i] = 0; }
    if (i == 0) { state[64] = Bn; state[65] = 0; }
}

// ---------------- weight repack: WB[cb][kq][lane][4] = M[4kq+c][64cb+lane] ----------------
// M = rows 0..511 -> Wx, 512..1023 -> Wh (both [512][2048]).  W4B same for W4 [512][512].
__global__ void wtrans_kernel(const float* __restrict__ Wx, const float* __restrict__ Wh,
                              const float* __restrict__ W4, float* __restrict__ WB,
                              float* __restrict__ W4B)
{
    int idx = blockIdx.x * 256 + threadIdx.x;
    if (idx < 2097152) {
        const int cc = idx & 3, l = (idx >> 2) & 63, kq = (idx >> 8) & 255, cb = idx >> 16;
        const int k = 4 * kq + cc, j = cb * 64 + l;
        WB[idx] = (k < 512) ? Wx[(long)k * G4 + j] : Wh[(long)(k - 512) * G4 + j];
    }
    if (idx < 262144) {
        const int cc = idx & 3, l = (idx >> 2) & 63, kq = (idx >> 8) & 127, cb = idx >> 15;
        const int k = 4 * kq + cc, j = cb * 64 + l;
        W4B[idx] = W4[(long)k * Wn + j];
    }
}

// ---------------- pe: prefix sums of inp over s ----------------
__global__ void pe_kernel(const int* __restrict__ wid, const float* __restrict__ emb,
                          float* __restrict__ pe)
{
    const int b = blockIdx.x;
    const int e = blockIdx.y * 256 + threadIdx.x;   // 0..511
    __shared__ int wids[Sn];
    for (int s = threadIdx.x; s < Sn; s += 256) wids[s] = wid[b * Sn + s];
    __syncthreads();
    float acc = 0.0f;
    float* base = pe + ((long)b * 257) * En + e;
    base[0] = 0.0f;
#pragma unroll 4
    for (int s = 0; s < Sn; ++s) {
        acc += emb[(long)wids[s] * En + e];
        base[(long)(s + 1) * En] = acc;
    }
}

// ---------------- bsum = enc@W1 + emb[wid]@W2 ----------------
__global__ __launch_bounds__(256) void bsum_gemm(
    const float* __restrict__ enc, const int* __restrict__ wid,
    const float* __restrict__ emb, const float* __restrict__ W1,
    const float* __restrict__ W2, float* __restrict__ bsum)
{
    __shared__ float As[16][68];
    __shared__ float Bs[16][68];
    const int tid  = threadIdx.x;
    const int row0 = blockIdx.y * 64;
    const int col0 = blockIdx.x * 64;
    const int tm0  = (tid & 15) * 4;
    const int tn0  = (tid >> 4) * 4;
    const int la_r = tid >> 2;
    const int la_k = (tid & 3) * 4;
    const int lb_k = tid >> 4;
    const int lb_n = (tid & 15) * 4;

    float acc[4][4];
#pragma unroll
    for (int i = 0; i < 4; i++)
#pragma unroll
        for (int j = 0; j < 4; j++) acc[i][j] = 0.0f;

    for (int k0 = 0; k0 < KTOT; k0 += 16) {
        const int gr = row0 + la_r;
        float4 av;
        if (k0 < ENCn) {
            av = *(const float4*)&enc[(long)gr * ENCn + k0 + la_k];
        } else {
            const int wv = wid[gr];
            av = *(const float4*)&emb[(long)wv * En + (k0 - ENCn) + la_k];
        }
        As[la_k + 0][la_r] = av.x;
        As[la_k + 1][la_r] = av.y;
        As[la_k + 2][la_r] = av.z;
        As[la_k + 3][la_r] = av.w;
        float4 bv;
        if (k0 < ENCn) bv = *(const float4*)&W1[(long)(k0 + lb_k) * Wn + col0 + lb_n];
        else           bv = *(const float4*)&W2[(long)(k0 - ENCn + lb_k) * Wn + col0 + lb_n];
        *(float4*)&Bs[lb_k][lb_n] = bv;
        __syncthreads();
#pragma unroll
        for (int kk = 0; kk < 16; kk++) {
            float4 a = *(const float4*)&As[kk][tm0];
            float4 b = *(const float4*)&Bs[kk][tn0];
            acc[0][0] += a.x * b.x; acc[0][1] += a.x * b.y; acc[0][2] += a.x * b.z; acc[0][3] += a.x * b.w;
            acc[1][0] += a.y * b.x; acc[1][1] += a.y * b.y; acc[1][2] += a.y * b.z; acc[1][3] += a.y * b.w;
            acc[2][0] += a.z * b.x; acc[2][1] += a.z * b.y; acc[2][2] += a.z * b.z; acc[2][3] += a.z * b.w;
            acc[3][0] += a.w * b.x; acc[3][1] += a.w * b.y; acc[3][2] += a.w * b.z; acc[3][3] += a.w * b.w;
        }
        __syncthreads();
    }
#pragma unroll
    for (int i = 0; i < 4; i++) {
        float4 o = make_float4(acc[i][0], acc[i][1], acc[i][2], acc[i][3]);
        *(float4*)&bsum[(long)(row0 + tm0 + i) * Wn + col0 + tn0] = o;
    }
}

// ---------------- u3 = emb[wid]@W3  (M=8192,N=512,K=512) ----------------
__global__ __launch_bounds__(256) void u3_gemm(
    const int* __restrict__ wid, const float* __restrict__ emb,
    const float* __restrict__ W3, float* __restrict__ u3)
{
    __shared__ float As[16][68];
    __shared__ float Bs[16][68];
    const int tid  = threadIdx.x;
    const int row0 = blockIdx.y * 64;
    const int col0 = blockIdx.x * 64;
    const int tm0  = (tid & 15) * 4;
    const int tn0  = (tid >> 4) * 4;
    const int la_r = tid >> 2;
    const int la_k = (tid & 3) * 4;
    const int lb_k = tid >> 4;
    const int lb_n = (tid & 15) * 4;

    float acc[4][4];
#pragma unroll
    for (int i = 0; i < 4; i++)
#pragma unroll
        for (int j = 0; j < 4; j++) acc[i][j] = 0.0f;

    for (int k0 = 0; k0 < 512; k0 += 16) {
        const int gr = row0 + la_r;
        const int wv = wid[gr];
        float4 av = *(const float4*)&emb[(long)wv * En + k0 + la_k];
        As[la_k + 0][la_r] = av.x;
        As[la_k + 1][la_r] = av.y;
        As[la_k + 2][la_r] = av.z;
        As[la_k + 3][la_r] = av.w;
        *(float4*)&Bs[lb_k][lb_n] = *(const float4*)&W3[(long)(k0 + lb_k) * Wn + col0 + lb_n];
        __syncthreads();
#pragma unroll
        for (int kk = 0; kk < 16; kk++) {
            float4 a = *(const float4*)&As[kk][tm0];
            float4 b = *(const float4*)&Bs[kk][tn0];
            acc[0][0] += a.x * b.x; acc[0][1] += a.x * b.y; acc[0][2] += a.x * b.z; acc[0][3] += a.x * b.w;
            acc[1][0] += a.y * b.x; acc[1][1] += a.y * b.y; acc[1][2] += a.y * b.z; acc[1][3] += a.y * b.w;
            acc[2][0] += a.z * b.x; acc[2][1] += a.z * b.y; acc[2][2] += a.z * b.z; acc[2][3] += a.z * b.w;
            acc[3][0] += a.w * b.x; acc[3][1] += a.w * b.y; acc[3][2] += a.w * b.z; acc[3][3] += a.w * b.w;
        }
        __syncthreads();
    }
#pragma unroll
    for (int i = 0; i < 4; i++) {
        float4 o = make_float4(acc[i][0], acc[i][1], acc[i][2], acc[i][3]);
        *(float4*)&u3[(long)(row0 + tm0 + i) * Wn + col0 + tn0] = o;
    }
}

// ---------------- lightweight grid barrier (monotone ticket) ----------------
__device__ __forceinline__ void gbar(int* bar, int nwg)
{
    __syncthreads();                       // drains vmem (stores visible at L2)
    if (threadIdx.x == 0) {
        __threadfence();                   // release
        int t = __hip_atomic_fetch_add(bar, 1, __ATOMIC_RELEASE, __HIP_MEMORY_SCOPE_AGENT);
        int target = (t / nwg + 1) * nwg;
        while (__hip_atomic_load(bar, __ATOMIC_ACQUIRE, __HIP_MEMORY_SCOPE_AGENT) < target)
            __builtin_amdgcn_s_sleep(1);
    }
    __syncthreads();
    __threadfence();                       // acquire: invalidate L1 so cross-CU data is fresh
}

// ---------------- persistent cooperative decode ----------------
// 256 WGs x 256 threads. Per step:
//   P1 (all WGs): gates[b][j] = x@Wx + h@Wh  (x from pe prefix diff)   -> gbar
//   P2 (32 WGs):  LSTM -> h2,c2; u4=h2@W4; scores over bsum+q; argmax; state -> gbar
__global__ __launch_bounds__(256) void decode_kernel(
    const float* __restrict__ bias, const float* __restrict__ vt1,
    const float* __restrict__ bsum, const float* __restrict__ u3,
    const float* __restrict__ pe,   const float* __restrict__ WB,
    const float* __restrict__ W4B,  float* __restrict__ gates,
    float* __restrict__ hbuf, float* __restrict__ cbuf,
    int* __restrict__ state, float* __restrict__ out)
{
    __shared__ float smem[4096];    // P1: staged (x|h)[4b][1024].  P2: sh2[512] | q[512] | scores[256]
    __shared__ float sv[256];
    __shared__ int   si[256];
    __shared__ int   sdone;

    const int wg   = blockIdx.x;
    const int tid  = threadIdx.x;
    const int lane = tid & 63;
    const int wv   = tid >> 6;
    int* bond = state;
    int* last = state + 32;
    int* nact = state + 64;
    int* bar  = state + 65;

    const int cb = wg & 31;     // P1 col block (64 cols of 2048)
    const int bg = wg >> 5;     // P1 batch group (4 batches)
    const float4* WB4  = (const float4*)WB;
    const float4* W4B4 = (const float4*)W4B;

    float vtv[8];
    if (wg < Bn) {
#pragma unroll
        for (int i = 0; i < 8; i++) vtv[i] = vt1[lane + 64 * i];
    }

    for (int step = 0; step < Sn; ++step) {
        // ======== P1: stage (x|h) for 4 batches, then GEMV ========
        for (int idx = tid; idx < 4096; idx += 256) {
            const int bq = idx >> 10, k = idx & 1023;
            const int b  = bg * 4 + bq;
            float v;
            if (k < 512) {
                const int bd = bond[b], ls = last[b];
                const float inv = 1.0f / (float)max(bd - ls, 1);
                v = (pe[((long)b * 257 + bd) * En + k] - pe[((long)b * 257 + ls) * En + k]) * inv;
            } else {
                v = hbuf[b * Hn + (k - 512)];
            }
            smem[idx] = v;   // layout [bq][1024]
        }
        __syncthreads();
        {
            float acc = 0.0f;
            const float* vbase = &smem[wv * 1024];
            const float4* wrow = WB4 + (long)cb * 256 * 64 + lane;
#pragma unroll 16
            for (int kq = 0; kq < 256; ++kq) {
                float4 w = wrow[kq * 64];
                float4 v = *(const float4*)&vbase[4 * kq];
                acc += w.x * v.x + w.y * v.y + w.z * v.z + w.w * v.w;
            }
            gates[(bg * 4 + wv) * G4 + cb * 64 + lane] = acc;
        }
        gbar(bar, 256);

        // ======== P2: one WG per batch ========
        if (wg < Bn) {
            const int b  = wg;
            const int bd = bond[b];
            if (bd < Sn) {
                // LSTM elementwise
                for (int j = tid; j < Hn; j += 256) {
                    const float ig = gates[b * G4 + j]        + bias[j];
                    const float fg = gates[b * G4 + 512 + j]  + bias[512 + j];
                    const float gg = gates[b * G4 + 1024 + j] + bias[1024 + j];
                    const float og = gates[b * G4 + 1536 + j] + bias[1536 + j];
                    const float co = cbuf[b * Hn + j];
                    const float sf  = 1.0f / (1.0f + expf(-fg));
                    const float sig = 1.0f / (1.0f + expf(-ig));
                    const float so  = 1.0f / (1.0f + expf(-og));
                    const float cn  = sf * co + sig * tanhf(gg);
                    const float h2  = so * tanhf(cn);
                    cbuf[b * Hn + j] = cn;
                    hbuf[b * Hn + j] = h2;
                    smem[j] = h2;                    // sh2
                }
                __syncthreads();
                // u4 = h2@W4 ; q = u4 + u3[b][bidx]
                const int bidx = bd < Sn ? bd : (Sn - 1);
                const float* u3row = u3 + ((long)b * Sn + bidx) * Wn;
#pragma unroll
                for (int bl = 0; bl < 2; ++bl) {
                    const int blk = wv * 2 + bl;     // 0..7
                    float acc = 0.0f;
                    const float4* wrow = W4B4 + (long)blk * 128 * 64 + lane;
#pragma unroll 16
                    for (int kq = 0; kq < 128; ++kq) {
                        float4 w = wrow[kq * 64];
                        float4 v = *(const float4*)&smem[4 * kq];
                        acc += w.x * v.x + w.y * v.y + w.z * v.z + w.w * v.w;
                    }
                    const int j = blk * 64 + lane;
                    smem[512 + j] = acc + u3row[j];  // q
                }
                __syncthreads();
                // scores over rows [bd, 256)
                const float* brow_base = bsum + (long)b * Sn * Wn;
                for (int p = bd + wv; p < Sn; p += 4) {
                    const float* row = brow_base + (long)p * Wn + lane;
                    float a = 0.0f;
#pragma unroll
                    for (int i = 0; i < 8; ++i)
                        a += tanhf(row[64 * i] + smem[512 + 64 * i + lane]) * vtv[i];
#pragma unroll
                    for (int off = 32; off; off >>= 1) a += __shfl_xor(a, off, 64);
                    if (lane == 0) smem[1024 + p] = a;
                }
                __syncthreads();
                // block argmax, first-index tie-break
                float v = -3.402823e38f; int vi = Sn;
                if (tid >= bd) { v = smem[1024 + tid]; vi = tid; }
                sv[tid] = v; si[tid] = vi;
                __syncthreads();
                for (int off = 128; off; off >>= 1) {
                    if (tid < off) {
                        const float v2 = sv[tid + off]; const int i2 = si[tid + off];
                        if (v2 > sv[tid] || (v2 == sv[tid] && i2 < si[tid])) { sv[tid] = v2; si[tid] = i2; }
                    }
                    __syncthreads();
                }
                if (tid == 0) {
                    const int idxm = si[0];
                    const int nb2 = (idxm > bd) ? idxm : (bd + 1);
                    if (nb2 < Sn) out[nb2 * Bn + b] = 1.0f;
                    else          atomicSub(nact, 1);
                    last[b] = bd;
                    bond[b] = nb2;
                }
            }
        }
        gbar(bar, 256);
        if (tid == 0) sdone = (__hip_atomic_load(nact, __ATOMIC_RELAXED, __HIP_MEMORY_SCOPE_AGENT) == 0);
        __syncthreads();
        if (sdone) break;
    }
}

extern "C" void kernel_launch(void* const* d_in, const int* in_sizes, int n_in,
                              void* d_out, int out_size, void* d_ws, size_t ws_size,
                              hipStream_t stream)
{
    const int*   wid  = (const int*)d_in[0];
    const float* enc  = (const float*)d_in[1];
    const float* hn0  = (const float*)d_in[2];
    const float* emb  = (const float*)d_in[3];
    // d_in[4] chunk_emb : unused (uniform score shift, argmax-invariant)
    const float* W1   = (const float*)d_in[5];
    const float* W2   = (const float*)d_in[6];
    const float* W3   = (const float*)d_in[7];
    const float* W4   = (const float*)d_in[8];
    const float* vt1  = (const float*)d_in[9];
    // d_in[10] vt2 : unused
    const float* Wx   = (const float*)d_in[11];
    const float* Wh   = (const float*)d_in[12];
    const float* bias = (const float*)d_in[13];

    float* ws    = (float*)d_ws;
    float* bsum  = ws + OFF_BSUM;
    float* u3    = ws + OFF_U3;
    float* pe    = ws + OFF_PE;
    float* WB    = ws + OFF_WB;
    float* W4B   = ws + OFF_W4B;
    float* gates = ws + OFF_GATES;
    float* h     = ws + OFF_H;
    float* c     = ws + OFF_C;
    int*   state = (int*)(ws + OFF_STATE);
    float* out   = (float*)d_out;

    hipMemsetAsync(d_out, 0, (size_t)Sn * Bn * sizeof(float), stream);
    hipLaunchKernelGGL(init_kernel, dim3(64), dim3(256), 0, stream, hn0, h, c, state);
    hipLaunchKernelGGL(wtrans_kernel, dim3(8192), dim3(256), 0, stream, Wx, Wh, W4, WB, W4B);
    hipLaunchKernelGGL(pe_kernel, dim3(32, 2), dim3(256), 0, stream, wid, emb, pe);
    hipLaunchKernelGGL(bsum_gemm, dim3(8, 128), dim3(256), 0, stream, enc, wid, emb, W1, W2, bsum);
    hipLaunchKernelGGL(u3_gemm, dim3(8, 128), dim3(256), 0, stream, wid, emb, W3, u3);

    void* args[] = { (void*)&bias, (void*)&vt1, (void*)&bsum, (void*)&u3, (void*)&pe,
                     (void*)&WB, (void*)&W4B, (void*)&gates, (void*)&h, (void*)&c,
                     (void*)&state, (void*)&out };
    hipLaunchCooperativeKernel((void*)decode_kernel, dim3(256), dim3(256), args, 0, stream);
}

// Round 3
// 1394.257 us; speedup vs baseline: 8.5104x; 8.5104x over previous
//
#include <hip/hip_runtime.h>
#include <math.h>

#define Bn   32
#define Sn   256
#define En   512
#define Hn   512
#define Wn   512
#define ENCn 1024
#define G4   2048
#define KTOT 1536
#define NC   8      // barrier clusters
#define WPC  32     // WGs per cluster

// ---------------- workspace layout (float offsets) ----------------
#define OFF_BSUM  0L            // [32][256][512]  4194304
#define OFF_U3    4194304L      // [32][256][512]  4194304  (pb overlays first 262144 during pe passes)
#define OFF_PE    8388608L      // [32][257][512]  4210688
#define OFF_WB    12599296L     // [32cb][256kq][64][4] 2097152
#define OFF_W4B   14696448L     // [8cb][128kq][64][4]   262144
#define OFF_GATES 14958592L     // [32][2048]      65536
#define OFF_H     15024128L     // [32][512]       16384
#define OFF_C     15040512L     // [32][512]       16384
#define OFF_SPART 15056896L     // [32][8][256]    65536
#define OFF_STATE 15122432L     // 4096 ints
// total 15126528 floats = 60.5 MB

// state ints: bond[0..31], last[32..63], nact@64, gcnt@80,
//             bcnt[b]@128+16b, cluster arrive@1024+256c, release@1024+256c+64

// ---------------- init ----------------
__global__ void init_kernel(const float* __restrict__ hn0, float* __restrict__ h,
                            float* __restrict__ c, int* __restrict__ state)
{
    int i = blockIdx.x * blockDim.x + threadIdx.x;
    if (i < Bn * Hn) { h[i] = 0.0f; c[i] = hn0[i]; }
    if (i < 4096) state[i] = (i == 64) ? Bn : 0;
}

// ---------------- weight repack ----------------
__global__ void wtrans_kernel(const float* __restrict__ Wx, const float* __restrict__ Wh,
                              const float* __restrict__ W4, float* __restrict__ WB,
                              float* __restrict__ W4B)
{
    int idx = blockIdx.x * 256 + threadIdx.x;
    if (idx < 2097152) {
        const int cc = idx & 3, l = (idx >> 2) & 63, kq = (idx >> 8) & 255, cb = idx >> 16;
        const int k = 4 * kq + cc, j = cb * 64 + l;
        WB[idx] = (k < 512) ? Wx[(long)k * G4 + j] : Wh[(long)(k - 512) * G4 + j];
    }
    if (idx < 262144) {
        const int cc = idx & 3, l = (idx >> 2) & 63, kq = (idx >> 8) & 127, cb = idx >> 15;
        const int k = 4 * kq + cc, j = cb * 64 + l;
        W4B[idx] = W4[(long)k * Wn + j];
    }
}

// ---------------- pe: parallel prefix sums of inp over s ----------------
__global__ void pe1_kernel(const int* __restrict__ wid, const float* __restrict__ emb,
                           float* __restrict__ pb)
{
    const int b = blockIdx.x, blk = blockIdx.y;
    __shared__ int wids[16];
    if (threadIdx.x < 16) wids[threadIdx.x] = wid[b * Sn + blk * 16 + threadIdx.x];
    __syncthreads();
    float a0 = 0.f, a1 = 0.f;
    for (int s = 0; s < 16; ++s) {
        const float* r = emb + (long)wids[s] * En;
        a0 += r[threadIdx.x]; a1 += r[threadIdx.x + 256];
    }
    pb[((long)b * 16 + blk) * En + threadIdx.x] = a0;
    pb[((long)b * 16 + blk) * En + threadIdx.x + 256] = a1;
}

__global__ void pe2_kernel(const int* __restrict__ wid, const float* __restrict__ emb,
                           const float* __restrict__ pb, float* __restrict__ pe)
{
    const int b = blockIdx.x, blk = blockIdx.y;
    __shared__ int wids[16];
    if (threadIdx.x < 16) wids[threadIdx.x] = wid[b * Sn + blk * 16 + threadIdx.x];
    __syncthreads();
    float a0 = 0.f, a1 = 0.f;
    for (int j = 0; j < blk; ++j) {
        a0 += pb[((long)b * 16 + j) * En + threadIdx.x];
        a1 += pb[((long)b * 16 + j) * En + threadIdx.x + 256];
    }
    float* base = pe + (long)b * 257 * En;
    if (blk == 0) { base[threadIdx.x] = 0.f; base[threadIdx.x + 256] = 0.f; }
    for (int s = 0; s < 16; ++s) {
        const float* r = emb + (long)wids[s] * En;
        a0 += r[threadIdx.x]; a1 += r[threadIdx.x + 256];
        float* o = base + (long)(blk * 16 + s + 1) * En;
        o[threadIdx.x] = a0; o[threadIdx.x + 256] = a1;
    }
}

// ---------------- bsum = enc@W1 + emb[wid]@W2 ----------------
__global__ __launch_bounds__(256) void bsum_gemm(
    const float* __restrict__ enc, const int* __restrict__ wid,
    const float* __restrict__ emb, const float* __restrict__ W1,
    const float* __restrict__ W2, float* __restrict__ bsum)
{
    __shared__ float As[16][68];
    __shared__ float Bs[16][68];
    const int tid  = threadIdx.x;
    const int row0 = blockIdx.y * 64;
    const int col0 = blockIdx.x * 64;
    const int tm0  = (tid & 15) * 4;
    const int tn0  = (tid >> 4) * 4;
    const int la_r = tid >> 2;
    const int la_k = (tid & 3) * 4;
    const int lb_k = tid >> 4;
    const int lb_n = (tid & 15) * 4;

    float acc[4][4];
#pragma unroll
    for (int i = 0; i < 4; i++)
#pragma unroll
        for (int j = 0; j < 4; j++) acc[i][j] = 0.0f;

    for (int k0 = 0; k0 < KTOT; k0 += 16) {
        const int gr = row0 + la_r;
        float4 av;
        if (k0 < ENCn) {
            av = *(const float4*)&enc[(long)gr * ENCn + k0 + la_k];
        } else {
            const int wv = wid[gr];
            av = *(const float4*)&emb[(long)wv * En + (k0 - ENCn) + la_k];
        }
        As[la_k + 0][la_r] = av.x;
        As[la_k + 1][la_r] = av.y;
        As[la_k + 2][la_r] = av.z;
        As[la_k + 3][la_r] = av.w;
        float4 bv;
        if (k0 < ENCn) bv = *(const float4*)&W1[(long)(k0 + lb_k) * Wn + col0 + lb_n];
        else           bv = *(const float4*)&W2[(long)(k0 - ENCn + lb_k) * Wn + col0 + lb_n];
        *(float4*)&Bs[lb_k][lb_n] = bv;
        __syncthreads();
#pragma unroll
        for (int kk = 0; kk < 16; kk++) {
            float4 a = *(const float4*)&As[kk][tm0];
            float4 b = *(const float4*)&Bs[kk][tn0];
            acc[0][0] += a.x * b.x; acc[0][1] += a.x * b.y; acc[0][2] += a.x * b.z; acc[0][3] += a.x * b.w;
            acc[1][0] += a.y * b.x; acc[1][1] += a.y * b.y; acc[1][2] += a.y * b.z; acc[1][3] += a.y * b.w;
            acc[2][0] += a.z * b.x; acc[2][1] += a.z * b.y; acc[2][2] += a.z * b.z; acc[2][3] += a.z * b.w;
            acc[3][0] += a.w * b.x; acc[3][1] += a.w * b.y; acc[3][2] += a.w * b.z; acc[3][3] += a.w * b.w;
        }
        __syncthreads();
    }
#pragma unroll
    for (int i = 0; i < 4; i++) {
        float4 o = make_float4(acc[i][0], acc[i][1], acc[i][2], acc[i][3]);
        *(float4*)&bsum[(long)(row0 + tm0 + i) * Wn + col0 + tn0] = o;
    }
}

// ---------------- u3 = emb[wid]@W3 ----------------
__global__ __launch_bounds__(256) void u3_gemm(
    const int* __restrict__ wid, const float* __restrict__ emb,
    const float* __restrict__ W3, float* __restrict__ u3)
{
    __shared__ float As[16][68];
    __shared__ float Bs[16][68];
    const int tid  = threadIdx.x;
    const int row0 = blockIdx.y * 64;
    const int col0 = blockIdx.x * 64;
    const int tm0  = (tid & 15) * 4;
    const int tn0  = (tid >> 4) * 4;
    const int la_r = tid >> 2;
    const int la_k = (tid & 3) * 4;
    const int lb_k = tid >> 4;
    const int lb_n = (tid & 15) * 4;

    float acc[4][4];
#pragma unroll
    for (int i = 0; i < 4; i++)
#pragma unroll
        for (int j = 0; j < 4; j++) acc[i][j] = 0.0f;

    for (int k0 = 0; k0 < 512; k0 += 16) {
        const int gr = row0 + la_r;
        const int wv = wid[gr];
        float4 av = *(const float4*)&emb[(long)wv * En + k0 + la_k];
        As[la_k + 0][la_r] = av.x;
        As[la_k + 1][la_r] = av.y;
        As[la_k + 2][la_r] = av.z;
        As[la_k + 3][la_r] = av.w;
        *(float4*)&Bs[lb_k][lb_n] = *(const float4*)&W3[(long)(k0 + lb_k) * Wn + col0 + lb_n];
        __syncthreads();
#pragma unroll
        for (int kk = 0; kk < 16; kk++) {
            float4 a = *(const float4*)&As[kk][tm0];
            float4 b = *(const float4*)&Bs[kk][tn0];
            acc[0][0] += a.x * b.x; acc[0][1] += a.x * b.y; acc[0][2] += a.x * b.z; acc[0][3] += a.x * b.w;
            acc[1][0] += a.y * b.x; acc[1][1] += a.y * b.y; acc[1][2] += a.y * b.z; acc[1][3] += a.y * b.w;
            acc[2][0] += a.z * b.x; acc[2][1] += a.z * b.y; acc[2][2] += a.z * b.z; acc[2][3] += a.z * b.w;
            acc[3][0] += a.w * b.x; acc[3][1] += a.w * b.y; acc[3][2] += a.w * b.z; acc[3][3] += a.w * b.w;
        }
        __syncthreads();
    }
#pragma unroll
    for (int i = 0; i < 4; i++) {
        float4 o = make_float4(acc[i][0], acc[i][1], acc[i][2], acc[i][3]);
        *(float4*)&u3[(long)(row0 + tm0 + i) * Wn + col0 + tn0] = o;
    }
}

// ---------------- 2-level grid barrier, relaxed polls + sleep backoff ----------------
// Returns uniform "all batches done" decided by the releasing WG (bit 30 of flag).
__device__ __forceinline__ int gbar(int* st, const int* nact, int wg, int round)
{
    __shared__ int s_done;
    __syncthreads();
    if (threadIdx.x == 0) {
        __threadfence();                                   // publish my data (wb L2)
        const int c = wg >> 5;
        int* lc = st + 1024 + 256 * c;
        int* lr = lc + 64;
        int flag = 0;
        bool wait = true;
        int a = __hip_atomic_fetch_add(lc, 1, __ATOMIC_RELAXED, __HIP_MEMORY_SCOPE_AGENT);
        if (a == round * WPC - 1) {                        // last in cluster
            int g = __hip_atomic_fetch_add(st + 80, 1, __ATOMIC_RELAXED, __HIP_MEMORY_SCOPE_AGENT);
            if (g == round * NC - 1) {                     // last overall -> release
                __threadfence();
                const int d = (__hip_atomic_load(nact, __ATOMIC_RELAXED, __HIP_MEMORY_SCOPE_AGENT) == 0) ? (1 << 30) : 0;
                flag = round | d;
                for (int k = 0; k < NC; ++k)
                    __hip_atomic_store(st + 1024 + 256 * k + 64, flag, __ATOMIC_RELAXED, __HIP_MEMORY_SCOPE_AGENT);
                wait = false;
            }
        }
        if (wait) {
            int it = 0;
            for (;;) {
                flag = __hip_atomic_load(lr, __ATOMIC_RELAXED, __HIP_MEMORY_SCOPE_AGENT);
                if ((flag & 0x3FFFFFFF) >= round) break;
                __builtin_amdgcn_s_sleep(2);
                if (((++it) & 31) == 0) __threadfence();   // liveness insurance
            }
        }
        __threadfence();                                   // acquire others' data
        s_done = (flag >> 30) & 1;
    }
    __syncthreads();
    return s_done;
}

// ---------------- persistent decode: 256 WGs x 256 thr ----------------
__global__ __launch_bounds__(256) void decode_kernel(
    const float* __restrict__ bias, const float* __restrict__ vt1,
    const float* __restrict__ bsum, const float* __restrict__ u3,
    const float* __restrict__ pe,   const float* __restrict__ WB,
    const float* __restrict__ W4B,  float* __restrict__ gates,
    float* __restrict__ hbuf, float* __restrict__ cbuf,
    float* __restrict__ spart,
    int* __restrict__ state, float* __restrict__ out)
{
    __shared__ __align__(16) float smem[5120];
    __shared__ float s_svt[64];
    __shared__ float s_wv[4];
    __shared__ int   s_wi[4];
    __shared__ int   s_last;

    const int wg   = blockIdx.x;
    const int tid  = threadIdx.x;
    const int lane = tid & 63;
    const int wv   = tid >> 6;

    int* bond = state;
    int* last = state + 32;
    int* nact = state + 64;

    const int cb1 = wg & 31;        // P1 col block (64 of 2048)
    const int bg  = wg >> 5;        // P1 batch group (4 batches)
    const int b2  = wg >> 3;        // P2 batch
    const int cb2 = wg & 7;         // P2 col block (64 of 512)
    const float4* WB4  = (const float4*)WB;
    const float4* W4B4 = (const float4*)W4B;

    if (tid < 64) s_svt[tid] = vt1[cb2 * 64 + tid];

    int myround = 0;

    for (int step = 0; step < Sn; ++step) {
        // ======== P1: gates = [x|h] @ [Wx;Wh], wave-split K + smem reduce ========
        for (int idx = tid; idx < 4096; idx += 256) {
            const int bq = idx >> 10, k = idx & 1023;
            const int b  = bg * 4 + bq;
            float v;
            if (k < En) {
                const int bd = bond[b], ls = last[b];
                const float inv = 1.0f / (float)max(bd - ls, 1);
                v = (pe[((long)b * 257 + bd) * En + k] - pe[((long)b * 257 + ls) * En + k]) * inv;
            } else {
                v = hbuf[b * Hn + (k - En)];
            }
            smem[idx] = v;              // [bq][1024]
        }
        __syncthreads();
        {
            float accs[4] = {0.f, 0.f, 0.f, 0.f};
            const float4* wrow = WB4 + ((long)cb1 * 256 + wv * 64) * 64 + lane;
#pragma unroll 8
            for (int kq = 0; kq < 64; ++kq) {
                const float4 w = wrow[(long)kq * 64];
                const int kb = (wv * 64 + kq) * 4;
#pragma unroll
                for (int bq = 0; bq < 4; ++bq) {
                    const float4 xv = *(const float4*)&smem[bq * 1024 + kb];
                    accs[bq] += w.x * xv.x + w.y * xv.y + w.z * xv.z + w.w * xv.w;
                }
            }
#pragma unroll
            for (int bq = 0; bq < 4; ++bq)
                smem[4096 + wv * 256 + bq * 64 + lane] = accs[bq];
        }
        __syncthreads();
        {
            const int bq = tid >> 6, l = tid & 63;
            const int b  = bg * 4 + bq;
            if (bond[b] < Sn) {
                const float s = smem[4096 +   0 + bq * 64 + l] + smem[4096 + 256 + bq * 64 + l]
                              + smem[4096 + 512 + bq * 64 + l] + smem[4096 + 768 + bq * 64 + l];
                gates[(long)b * G4 + cb1 * 64 + l] = s;
            }
        }
        gbar(state, nact, wg, 2 * step + 1);

        // ======== P2: (batch, 64-col slice) on all 256 WGs ========
        const int bd = bond[b2];
        if (bd < Sn) {
            ++myround;
            // LSTM (redundant across the 8 WGs of this batch)
            for (int j = tid; j < Hn; j += 256) {
                const float ig = gates[(long)b2 * G4 + j]        + bias[j];
                const float fg = gates[(long)b2 * G4 + 512 + j]  + bias[512 + j];
                const float gg = gates[(long)b2 * G4 + 1024 + j] + bias[1024 + j];
                const float og = gates[(long)b2 * G4 + 1536 + j] + bias[1536 + j];
                const float co = cbuf[b2 * Hn + j];
                const float sf  = 1.f / (1.f + expf(-fg));
                const float sig = 1.f / (1.f + expf(-ig));
                const float so  = 1.f / (1.f + expf(-og));
                const float cn  = sf * co + sig * tanhf(gg);
                const float h2  = so * tanhf(cn);
                smem[j] = h2;
                if (cb2 == 0) { hbuf[b2 * Hn + j] = h2; cbuf[b2 * Hn + j] = cn; }
            }
            __syncthreads();
            // u4 slice (64 cols), wave-split K
            {
                float acc = 0.f;
                const float4* wrow = W4B4 + ((long)cb2 * 128 + wv * 32) * 64 + lane;
#pragma unroll 8
                for (int kq = 0; kq < 32; ++kq) {
                    const float4 w  = wrow[(long)kq * 64];
                    const float4 xv = *(const float4*)&smem[(wv * 32 + kq) * 4];
                    acc += w.x * xv.x + w.y * xv.y + w.z * xv.z + w.w * xv.w;
                }
                smem[512 + wv * 64 + lane] = acc;
            }
            __syncthreads();
            if (tid < 64) {
                const float* u3row = u3 + ((long)b2 * Sn + bd) * Wn + cb2 * 64;
                smem[768 + tid] = smem[512 + tid] + smem[576 + tid] + smem[640 + tid]
                                + smem[704 + tid] + u3row[tid];
            }
            __syncthreads();
            // partial scores: thread tid = row p
            if (tid >= bd) {
                const float* row = bsum + ((long)b2 * Sn + tid) * Wn + cb2 * 64;
                float a = 0.f;
#pragma unroll 8
                for (int i = 0; i < 64; ++i)
                    a += tanhf(row[i] + smem[768 + i]) * s_svt[i];
                spart[((long)b2 * 8 + cb2) * 256 + tid] = a;
            }
            __syncthreads();
            if (tid == 0) {
                __threadfence();
                int o = __hip_atomic_fetch_add(state + 128 + 16 * b2, 1,
                                               __ATOMIC_RELAXED, __HIP_MEMORY_SCOPE_AGENT);
                s_last = (o == myround * 8 - 1);
                if (s_last) __threadfence();
            }
            __syncthreads();
            if (s_last) {
                // sum 8 partials (fixed order) + argmax, first-index tie-break
                float v = -3.402823e38f; int vi = Sn;
                if (tid >= bd) {
                    const float* sp = spart + (long)b2 * 8 * 256 + tid;
                    float s = 0.f;
#pragma unroll
                    for (int k = 0; k < 8; ++k) s += sp[k * 256];
                    v = s; vi = tid;
                }
#pragma unroll
                for (int off = 32; off; off >>= 1) {
                    const float v2 = __shfl_xor(v, off, 64);
                    const int   i2 = __shfl_xor(vi, off, 64);
                    if (v2 > v || (v2 == v && i2 < vi)) { v = v2; vi = i2; }
                }
                if (lane == 0) { s_wv[wv] = v; s_wi[wv] = vi; }
                __syncthreads();
                if (tid == 0) {
                    float bv = s_wv[0]; int bi = s_wi[0];
#pragma unroll
                    for (int k = 1; k < 4; ++k)
                        if (s_wv[k] > bv || (s_wv[k] == bv && s_wi[k] < bi)) { bv = s_wv[k]; bi = s_wi[k]; }
                    const int nb2 = (bi > bd) ? bi : bd + 1;
                    if (nb2 < Sn) out[nb2 * Bn + b2] = 1.0f;
                    else __hip_atomic_fetch_add(nact, -1, __ATOMIC_RELAXED, __HIP_MEMORY_SCOPE_AGENT);
                    last[b2] = bd;
                    bond[b2] = nb2;
                }
            }
        }
        if (gbar(state, nact, wg, 2 * step + 2)) break;
    }
}

extern "C" void kernel_launch(void* const* d_in, const int* in_sizes, int n_in,
                              void* d_out, int out_size, void* d_ws, size_t ws_size,
                              hipStream_t stream)
{
    const int*   wid  = (const int*)d_in[0];
    const float* enc  = (const float*)d_in[1];
    const float* hn0  = (const float*)d_in[2];
    const float* emb  = (const float*)d_in[3];
    // d_in[4] chunk_emb : unused (uniform score shift, argmax-invariant)
    const float* W1   = (const float*)d_in[5];
    const float* W2   = (const float*)d_in[6];
    const float* W3   = (const float*)d_in[7];
    const float* W4   = (const float*)d_in[8];
    const float* vt1  = (const float*)d_in[9];
    // d_in[10] vt2 : unused
    const float* Wx   = (const float*)d_in[11];
    const float* Wh   = (const float*)d_in[12];
    const float* bias = (const float*)d_in[13];

    float* ws    = (float*)d_ws;
    float* bsum  = ws + OFF_BSUM;
    float* u3    = ws + OFF_U3;
    float* pb    = ws + OFF_U3;       // overlay: used only before u3_gemm
    float* pe    = ws + OFF_PE;
    float* WB    = ws + OFF_WB;
    float* W4B   = ws + OFF_W4B;
    float* gates = ws + OFF_GATES;
    float* h     = ws + OFF_H;
    float* c     = ws + OFF_C;
    float* spart = ws + OFF_SPART;
    int*   state = (int*)(ws + OFF_STATE);
    float* out   = (float*)d_out;

    hipMemsetAsync(d_out, 0, (size_t)Sn * Bn * sizeof(float), stream);
    hipLaunchKernelGGL(init_kernel, dim3(64), dim3(256), 0, stream, hn0, h, c, state);
    hipLaunchKernelGGL(wtrans_kernel, dim3(8192), dim3(256), 0, stream, Wx, Wh, W4, WB, W4B);
    hipLaunchKernelGGL(pe1_kernel, dim3(32, 16), dim3(256), 0, stream, wid, emb, pb);
    hipLaunchKernelGGL(pe2_kernel, dim3(32, 16), dim3(256), 0, stream, wid, emb, pb, pe);
    hipLaunchKernelGGL(u3_gemm, dim3(8, 128), dim3(256), 0, stream, wid, emb, W3, u3);
    hipLaunchKernelGGL(bsum_gemm, dim3(8, 128), dim3(256), 0, stream, enc, wid, emb, W1, W2, bsum);

    void* args[] = { (void*)&bias, (void*)&vt1, (void*)&bsum, (void*)&u3, (void*)&pe,
                     (void*)&WB, (void*)&W4B, (void*)&gates, (void*)&h, (void*)&c,
                     (void*)&spart, (void*)&state, (void*)&out };
    hipLaunchCooperativeKernel((void*)decode_kernel, dim3(256), dim3(256), args, 0, stream);
}

// Round 4
// 1023.326 us; speedup vs baseline: 11.5952x; 1.3625x over previous
//
#include <hip/hip_runtime.h>
#include <math.h>

#define Bn   32
#define Sn   256
#define En   512
#define Hn   512
#define Wn   512
#define ENCn 1024
#define G4   2048
#define KTOT 1536
#define NC   8      // barrier clusters
#define WPC  32     // WGs per cluster

// ---------------- workspace layout (float offsets) ----------------
#define OFF_BSUM  0L            // [32][256][512]  4194304
#define OFF_U3    4194304L      // [32][256][512]  4194304  (pb overlays first 262144 during pe passes)
#define OFF_PE    8388608L      // [32][257][512]  4210688
#define OFF_WB    12599296L     // [32cb][256kq][64][4] 2097152
#define OFF_W4B   14696448L     // [8cb][128kq][64][4]   262144
#define OFF_GATES 14958592L     // [32][2048]      65536
#define OFF_H     15024128L     // [32][512]       16384
#define OFF_C     15040512L     // [2][32][512]    32768 (ping-pong)
#define OFF_SPART 15073280L     // [32][8][256]    65536
#define OFF_STATE 15138816L     // 8192 ints
// total 15147008 floats ~= 60.6 MB

// state ints: bond[0..31], last[32..63], nact@64, gcnt@80,
//             bcnt[b]@256+64b, cluster arrive@4096+256c, release@4096+256c+64

// ---------------- coherent (IF-level) access helpers ----------------
__device__ __forceinline__ float aload(const float* p) {
    return __hip_atomic_load(p, __ATOMIC_RELAXED, __HIP_MEMORY_SCOPE_AGENT);
}
__device__ __forceinline__ void astore(float* p, float v) {
    __hip_atomic_store(p, v, __ATOMIC_RELAXED, __HIP_MEMORY_SCOPE_AGENT);
}
__device__ __forceinline__ int aiload(const int* p) {
    return __hip_atomic_load(p, __ATOMIC_RELAXED, __HIP_MEMORY_SCOPE_AGENT);
}
__device__ __forceinline__ void aistore(int* p, int v) {
    __hip_atomic_store(p, v, __ATOMIC_RELAXED, __HIP_MEMORY_SCOPE_AGENT);
}

// ---------------- init ----------------
__global__ void init_kernel(const float* __restrict__ hn0, float* __restrict__ h,
                            float* __restrict__ c, int* __restrict__ state)
{
    int i = blockIdx.x * blockDim.x + threadIdx.x;
    if (i < Bn * Hn) { h[i] = 0.0f; c[i] = hn0[i]; }
    if (i < 8192) state[i] = (i == 64) ? Bn : 0;
}

// ---------------- weight repack ----------------
__global__ void wtrans_kernel(const float* __restrict__ Wx, const float* __restrict__ Wh,
                              const float* __restrict__ W4, float* __restrict__ WB,
                              float* __restrict__ W4B)
{
    int idx = blockIdx.x * 256 + threadIdx.x;
    if (idx < 2097152) {
        const int cc = idx & 3, l = (idx >> 2) & 63, kq = (idx >> 8) & 255, cb = idx >> 16;
        const int k = 4 * kq + cc, j = cb * 64 + l;
        WB[idx] = (k < 512) ? Wx[(long)k * G4 + j] : Wh[(long)(k - 512) * G4 + j];
    }
    if (idx < 262144) {
        const int cc = idx & 3, l = (idx >> 2) & 63, kq = (idx >> 8) & 127, cb = idx >> 15;
        const int k = 4 * kq + cc, j = cb * 64 + l;
        W4B[idx] = W4[(long)k * Wn + j];
    }
}

// ---------------- pe: parallel prefix sums of inp over s ----------------
__global__ void pe1_kernel(const int* __restrict__ wid, const float* __restrict__ emb,
                           float* __restrict__ pb)
{
    const int b = blockIdx.x, blk = blockIdx.y;
    __shared__ int wids[16];
    if (threadIdx.x < 16) wids[threadIdx.x] = wid[b * Sn + blk * 16 + threadIdx.x];
    __syncthreads();
    float a0 = 0.f, a1 = 0.f;
    for (int s = 0; s < 16; ++s) {
        const float* r = emb + (long)wids[s] * En;
        a0 += r[threadIdx.x]; a1 += r[threadIdx.x + 256];
    }
    pb[((long)b * 16 + blk) * En + threadIdx.x] = a0;
    pb[((long)b * 16 + blk) * En + threadIdx.x + 256] = a1;
}

__global__ void pe2_kernel(const int* __restrict__ wid, const float* __restrict__ emb,
                           const float* __restrict__ pb, float* __restrict__ pe)
{
    const int b = blockIdx.x, blk = blockIdx.y;
    __shared__ int wids[16];
    if (threadIdx.x < 16) wids[threadIdx.x] = wid[b * Sn + blk * 16 + threadIdx.x];
    __syncthreads();
    float a0 = 0.f, a1 = 0.f;
    for (int j = 0; j < blk; ++j) {
        a0 += pb[((long)b * 16 + j) * En + threadIdx.x];
        a1 += pb[((long)b * 16 + j) * En + threadIdx.x + 256];
    }
    float* base = pe + (long)b * 257 * En;
    if (blk == 0) { base[threadIdx.x] = 0.f; base[threadIdx.x + 256] = 0.f; }
    for (int s = 0; s < 16; ++s) {
        const float* r = emb + (long)wids[s] * En;
        a0 += r[threadIdx.x]; a1 += r[threadIdx.x + 256];
        float* o = base + (long)(blk * 16 + s + 1) * En;
        o[threadIdx.x] = a0; o[threadIdx.x + 256] = a1;
    }
}

// ---------------- bsum = enc@W1 + emb[wid]@W2 ----------------
__global__ __launch_bounds__(256) void bsum_gemm(
    const float* __restrict__ enc, const int* __restrict__ wid,
    const float* __restrict__ emb, const float* __restrict__ W1,
    const float* __restrict__ W2, float* __restrict__ bsum)
{
    __shared__ float As[16][68];
    __shared__ float Bs[16][68];
    const int tid  = threadIdx.x;
    const int row0 = blockIdx.y * 64;
    const int col0 = blockIdx.x * 64;
    const int tm0  = (tid & 15) * 4;
    const int tn0  = (tid >> 4) * 4;
    const int la_r = tid >> 2;
    const int la_k = (tid & 3) * 4;
    const int lb_k = tid >> 4;
    const int lb_n = (tid & 15) * 4;

    float acc[4][4];
#pragma unroll
    for (int i = 0; i < 4; i++)
#pragma unroll
        for (int j = 0; j < 4; j++) acc[i][j] = 0.0f;

    for (int k0 = 0; k0 < KTOT; k0 += 16) {
        const int gr = row0 + la_r;
        float4 av;
        if (k0 < ENCn) {
            av = *(const float4*)&enc[(long)gr * ENCn + k0 + la_k];
        } else {
            const int wv = wid[gr];
            av = *(const float4*)&emb[(long)wv * En + (k0 - ENCn) + la_k];
        }
        As[la_k + 0][la_r] = av.x;
        As[la_k + 1][la_r] = av.y;
        As[la_k + 2][la_r] = av.z;
        As[la_k + 3][la_r] = av.w;
        float4 bv;
        if (k0 < ENCn) bv = *(const float4*)&W1[(long)(k0 + lb_k) * Wn + col0 + lb_n];
        else           bv = *(const float4*)&W2[(long)(k0 - ENCn + lb_k) * Wn + col0 + lb_n];
        *(float4*)&Bs[lb_k][lb_n] = bv;
        __syncthreads();
#pragma unroll
        for (int kk = 0; kk < 16; kk++) {
            float4 a = *(const float4*)&As[kk][tm0];
            float4 b = *(const float4*)&Bs[kk][tn0];
            acc[0][0] += a.x * b.x; acc[0][1] += a.x * b.y; acc[0][2] += a.x * b.z; acc[0][3] += a.x * b.w;
            acc[1][0] += a.y * b.x; acc[1][1] += a.y * b.y; acc[1][2] += a.y * b.z; acc[1][3] += a.y * b.w;
            acc[2][0] += a.z * b.x; acc[2][1] += a.z * b.y; acc[2][2] += a.z * b.z; acc[2][3] += a.z * b.w;
            acc[3][0] += a.w * b.x; acc[3][1] += a.w * b.y; acc[3][2] += a.w * b.z; acc[3][3] += a.w * b.w;
        }
        __syncthreads();
    }
#pragma unroll
    for (int i = 0; i < 4; i++) {
        float4 o = make_float4(acc[i][0], acc[i][1], acc[i][2], acc[i][3]);
        *(float4*)&bsum[(long)(row0 + tm0 + i) * Wn + col0 + tn0] = o;
    }
}

// ---------------- u3 = emb[wid]@W3 ----------------
__global__ __launch_bounds__(256) void u3_gemm(
    const int* __restrict__ wid, const float* __restrict__ emb,
    const float* __restrict__ W3, float* __restrict__ u3)
{
    __shared__ float As[16][68];
    __shared__ float Bs[16][68];
    const int tid  = threadIdx.x;
    const int row0 = blockIdx.y * 64;
    const int col0 = blockIdx.x * 64;
    const int tm0  = (tid & 15) * 4;
    const int tn0  = (tid >> 4) * 4;
    const int la_r = tid >> 2;
    const int la_k = (tid & 3) * 4;
    const int lb_k = tid >> 4;
    const int lb_n = (tid & 15) * 4;

    float acc[4][4];
#pragma unroll
    for (int i = 0; i < 4; i++)
#pragma unroll
        for (int j = 0; j < 4; j++) acc[i][j] = 0.0f;

    for (int k0 = 0; k0 < 512; k0 += 16) {
        const int gr = row0 + la_r;
        const int wv = wid[gr];
        float4 av = *(const float4*)&emb[(long)wv * En + k0 + la_k];
        As[la_k + 0][la_r] = av.x;
        As[la_k + 1][la_r] = av.y;
        As[la_k + 2][la_r] = av.z;
        As[la_k + 3][la_r] = av.w;
        *(float4*)&Bs[lb_k][lb_n] = *(const float4*)&W3[(long)(k0 + lb_k) * Wn + col0 + lb_n];
        __syncthreads();
#pragma unroll
        for (int kk = 0; kk < 16; kk++) {
            float4 a = *(const float4*)&As[kk][tm0];
            float4 b = *(const float4*)&Bs[kk][tn0];
            acc[0][0] += a.x * b.x; acc[0][1] += a.x * b.y; acc[0][2] += a.x * b.z; acc[0][3] += a.x * b.w;
            acc[1][0] += a.y * b.x; acc[1][1] += a.y * b.y; acc[1][2] += a.y * b.z; acc[1][3] += a.y * b.w;
            acc[2][0] += a.z * b.x; acc[2][1] += a.z * b.y; acc[2][2] += a.z * b.z; acc[2][3] += a.z * b.w;
            acc[3][0] += a.w * b.x; acc[3][1] += a.w * b.y; acc[3][2] += a.w * b.z; acc[3][3] += a.w * b.w;
        }
        __syncthreads();
    }
#pragma unroll
    for (int i = 0; i < 4; i++) {
        float4 o = make_float4(acc[i][0], acc[i][1], acc[i][2], acc[i][3]);
        *(float4*)&u3[(long)(row0 + tm0 + i) * Wn + col0 + tn0] = o;
    }
}

// ---------------- 2-level grid barrier: relaxed coherent atomics, ZERO fences ----------------
// __syncthreads() at entry drains vmcnt -> all prior sc1 stores are globally visible.
__device__ __forceinline__ int gbar(int* st, const int* nact, int wg, int round)
{
    __shared__ int s_done;
    __syncthreads();
    if (threadIdx.x == 0) {
        const int c = wg >> 5;
        int* lc = st + 4096 + 256 * c;
        int* lr = lc + 64;
        int flag = 0;
        bool wait = true;
        int a = __hip_atomic_fetch_add(lc, 1, __ATOMIC_RELAXED, __HIP_MEMORY_SCOPE_AGENT);
        if (a == round * WPC - 1) {                        // last in cluster
            int g = __hip_atomic_fetch_add(st + 80, 1, __ATOMIC_RELAXED, __HIP_MEMORY_SCOPE_AGENT);
            if (g == round * NC - 1) {                     // last overall -> release
                const int d = (aiload(nact) == 0) ? (1 << 30) : 0;
                flag = round | d;
                for (int k = 0; k < NC; ++k)
                    aistore(st + 4096 + 256 * k + 64, flag);
                wait = false;
            }
        }
        if (wait) {
            for (;;) {
                flag = aiload(lr);
                if ((flag & 0x3FFFFFFF) >= round) break;
                __builtin_amdgcn_s_sleep(1);
            }
        }
        s_done = (flag >> 30) & 1;
    }
    __syncthreads();
    return s_done;
}

// ---------------- persistent decode: 256 WGs x 256 thr ----------------
__global__ __launch_bounds__(256) void decode_kernel(
    const float* __restrict__ bias, const float* __restrict__ vt1,
    const float* __restrict__ bsum, const float* __restrict__ u3,
    const float* __restrict__ pe,   const float* __restrict__ WB,
    const float* __restrict__ W4B,  float* __restrict__ gates,
    float* __restrict__ hbuf, float* __restrict__ cbuf,
    float* __restrict__ spart,
    int* __restrict__ state, float* __restrict__ out)
{
    __shared__ __align__(16) float smem[5120];
    __shared__ float s_svt[64];
    __shared__ float s_wv[4];
    __shared__ int   s_wi[4];
    __shared__ int   s_last;
    __shared__ int   s_bd[4], s_ls[4];

    const int wg   = blockIdx.x;
    const int tid  = threadIdx.x;
    const int lane = tid & 63;
    const int wv   = tid >> 6;

    int* bond = state;
    int* last = state + 32;
    int* nact = state + 64;

    const int cb1 = wg & 31;        // P1 col block (64 of 2048)
    const int bg  = wg >> 5;        // P1 batch group (4 batches)
    const int b2  = wg >> 3;        // P2 batch
    const int cb2 = wg & 7;         // P2 col block (64 of 512)
    const float4* WB4  = (const float4*)WB;
    const float4* W4B4 = (const float4*)W4B;

    if (tid < 64) s_svt[tid] = vt1[cb2 * 64 + tid];

    int myround = 0;

    for (int step = 0; step < Sn; ++step) {
        const float* cold = cbuf + (step & 1) * (Bn * Hn);
        float*       cnew = cbuf + ((step + 1) & 1) * (Bn * Hn);

        // ======== P1: gates = [x|h] @ [Wx;Wh], wave-split K + smem reduce ========
        if (tid < 4) {
            s_bd[tid] = aiload(&bond[bg * 4 + tid]);
            s_ls[tid] = aiload(&last[bg * 4 + tid]);
        }
        __syncthreads();
        for (int idx = tid; idx < 4096; idx += 256) {
            const int bq = idx >> 10, k = idx & 1023;
            const int b  = bg * 4 + bq;
            float v;
            if (k < En) {
                const int bd = s_bd[bq], ls = s_ls[bq];
                const float inv = 1.0f / (float)max(bd - ls, 1);
                v = (pe[((long)b * 257 + bd) * En + k] - pe[((long)b * 257 + ls) * En + k]) * inv;
            } else {
                v = aload(&hbuf[b * Hn + (k - En)]);
            }
            smem[idx] = v;              // [bq][1024]
        }
        __syncthreads();
        {
            float accs[4] = {0.f, 0.f, 0.f, 0.f};
            const float4* wrow = WB4 + ((long)cb1 * 256 + wv * 64) * 64 + lane;
#pragma unroll 8
            for (int kq = 0; kq < 64; ++kq) {
                const float4 w = wrow[(long)kq * 64];
                const int kb = (wv * 64 + kq) * 4;
#pragma unroll
                for (int bq = 0; bq < 4; ++bq) {
                    const float4 xv = *(const float4*)&smem[bq * 1024 + kb];
                    accs[bq] += w.x * xv.x + w.y * xv.y + w.z * xv.z + w.w * xv.w;
                }
            }
#pragma unroll
            for (int bq = 0; bq < 4; ++bq)
                smem[4096 + wv * 256 + bq * 64 + lane] = accs[bq];
        }
        __syncthreads();
        {
            const int bq = tid >> 6, l = tid & 63;
            const int b  = bg * 4 + bq;
            if (s_bd[bq] < Sn) {
                const float s = smem[4096 +   0 + bq * 64 + l] + smem[4096 + 256 + bq * 64 + l]
                              + smem[4096 + 512 + bq * 64 + l] + smem[4096 + 768 + bq * 64 + l];
                astore(&gates[(long)b * G4 + cb1 * 64 + l], s);
            }
        }
        gbar(state, nact, wg, 2 * step + 1);

        // ======== P2: (batch, 64-col slice) on all 256 WGs ========
        const int bd = aiload(&bond[b2]);
        if (bd < Sn) {
            ++myround;
            // LSTM (redundant across the 8 WGs of this batch); c ping-pong kills the in-step race
            for (int j = tid; j < Hn; j += 256) {
                const float ig = aload(&gates[(long)b2 * G4 + j])        + bias[j];
                const float fg = aload(&gates[(long)b2 * G4 + 512 + j])  + bias[512 + j];
                const float gg = aload(&gates[(long)b2 * G4 + 1024 + j]) + bias[1024 + j];
                const float og = aload(&gates[(long)b2 * G4 + 1536 + j]) + bias[1536 + j];
                const float co = aload(&cold[b2 * Hn + j]);
                const float sf  = 1.f / (1.f + expf(-fg));
                const float sig = 1.f / (1.f + expf(-ig));
                const float so  = 1.f / (1.f + expf(-og));
                const float cn  = sf * co + sig * tanhf(gg);
                const float h2  = so * tanhf(cn);
                smem[j] = h2;
                if (cb2 == 0) { astore(&hbuf[b2 * Hn + j], h2); astore(&cnew[b2 * Hn + j], cn); }
            }
            __syncthreads();
            // u4 slice (64 cols), wave-split K
            {
                float acc = 0.f;
                const float4* wrow = W4B4 + ((long)cb2 * 128 + wv * 32) * 64 + lane;
#pragma unroll 8
                for (int kq = 0; kq < 32; ++kq) {
                    const float4 w  = wrow[(long)kq * 64];
                    const float4 xv = *(const float4*)&smem[(wv * 32 + kq) * 4];
                    acc += w.x * xv.x + w.y * xv.y + w.z * xv.z + w.w * xv.w;
                }
                smem[512 + wv * 64 + lane] = acc;
            }
            __syncthreads();
            if (tid < 64) {
                const float* u3row = u3 + ((long)b2 * Sn + bd) * Wn + cb2 * 64;
                smem[768 + tid] = smem[512 + tid] + smem[576 + tid] + smem[640 + tid]
                                + smem[704 + tid] + u3row[tid];
            }
            __syncthreads();
            // partial scores: thread tid = row p
            if (tid >= bd) {
                const float* row = bsum + ((long)b2 * Sn + tid) * Wn + cb2 * 64;
                float a = 0.f;
#pragma unroll 8
                for (int i = 0; i < 64; ++i)
                    a += tanhf(row[i] + smem[768 + i]) * s_svt[i];
                astore(&spart[((long)b2 * 8 + cb2) * 256 + tid], a);
            }
            __syncthreads();                 // drains spart sc1 stores
            if (tid == 0) {
                int o = __hip_atomic_fetch_add(state + 256 + 64 * b2, 1,
                                               __ATOMIC_RELAXED, __HIP_MEMORY_SCOPE_AGENT);
                s_last = (o == myround * 8 - 1);
            }
            __syncthreads();
            if (s_last) {
                // sum 8 partials (fixed order) + argmax, first-index tie-break
                float v = -3.402823e38f; int vi = Sn;
                if (tid >= bd) {
                    const float* sp = spart + (long)b2 * 8 * 256 + tid;
                    float s = 0.f;
#pragma unroll
                    for (int k = 0; k < 8; ++k) s += aload(&sp[k * 256]);
                    v = s; vi = tid;
                }
#pragma unroll
                for (int off = 32; off; off >>= 1) {
                    const float v2 = __shfl_xor(v, off, 64);
                    const int   i2 = __shfl_xor(vi, off, 64);
                    if (v2 > v || (v2 == v && i2 < vi)) { v = v2; vi = i2; }
                }
                if (lane == 0) { s_wv[wv] = v; s_wi[wv] = vi; }
                __syncthreads();
                if (tid == 0) {
                    float bv = s_wv[0]; int bi = s_wi[0];
#pragma unroll
                    for (int k = 1; k < 4; ++k)
                        if (s_wv[k] > bv || (s_wv[k] == bv && s_wi[k] < bi)) { bv = s_wv[k]; bi = s_wi[k]; }
                    const int nb2 = (bi > bd) ? bi : bd + 1;
                    if (nb2 < Sn) out[nb2 * Bn + b2] = 1.0f;
                    else __hip_atomic_fetch_add(nact, -1, __ATOMIC_RELAXED, __HIP_MEMORY_SCOPE_AGENT);
                    aistore(&last[b2], bd);
                    aistore(&bond[b2], nb2);
                }
            }
        }
        if (gbar(state, nact, wg, 2 * step + 2)) break;
    }
}

extern "C" void kernel_launch(void* const* d_in, const int* in_sizes, int n_in,
                              void* d_out, int out_size, void* d_ws, size_t ws_size,
                              hipStream_t stream)
{
    const int*   wid  = (const int*)d_in[0];
    const float* enc  = (const float*)d_in[1];
    const float* hn0  = (const float*)d_in[2];
    const float* emb  = (const float*)d_in[3];
    // d_in[4] chunk_emb : unused (uniform score shift, argmax-invariant)
    const float* W1   = (const float*)d_in[5];
    const float* W2   = (const float*)d_in[6];
    const float* W3   = (const float*)d_in[7];
    const float* W4   = (const float*)d_in[8];
    const float* vt1  = (const float*)d_in[9];
    // d_in[10] vt2 : unused
    const float* Wx   = (const float*)d_in[11];
    const float* Wh   = (const float*)d_in[12];
    const float* bias = (const float*)d_in[13];

    float* ws    = (float*)d_ws;
    float* bsum  = ws + OFF_BSUM;
    float* u3    = ws + OFF_U3;
    float* pb    = ws + OFF_U3;       // overlay: used only before u3_gemm
    float* pe    = ws + OFF_PE;
    float* WB    = ws + OFF_WB;
    float* W4B   = ws + OFF_W4B;
    float* gates = ws + OFF_GATES;
    float* h     = ws + OFF_H;
    float* c     = ws + OFF_C;
    float* spart = ws + OFF_SPART;
    int*   state = (int*)(ws + OFF_STATE);
    float* out   = (float*)d_out;

    hipMemsetAsync(d_out, 0, (size_t)Sn * Bn * sizeof(float), stream);
    hipLaunchKernelGGL(init_kernel, dim3(64), dim3(256), 0, stream, hn0, h, c, state);
    hipLaunchKernelGGL(wtrans_kernel, dim3(8192), dim3(256), 0, stream, Wx, Wh, W4, WB, W4B);
    hipLaunchKernelGGL(pe1_kernel, dim3(32, 16), dim3(256), 0, stream, wid, emb, pb);
    hipLaunchKernelGGL(pe2_kernel, dim3(32, 16), dim3(256), 0, stream, wid, emb, pb, pe);
    hipLaunchKernelGGL(u3_gemm, dim3(8, 128), dim3(256), 0, stream, wid, emb, W3, u3);
    hipLaunchKernelGGL(bsum_gemm, dim3(8, 128), dim3(256), 0, stream, enc, wid, emb, W1, W2, bsum);

    void* args[] = { (void*)&bias, (void*)&vt1, (void*)&bsum, (void*)&u3, (void*)&pe,
                     (void*)&WB, (void*)&W4B, (void*)&gates, (void*)&h, (void*)&c,
                     (void*)&spart, (void*)&state, (void*)&out };
    hipLaunchCooperativeKernel((void*)decode_kernel, dim3(256), dim3(256), args, 0, stream);
}

// Round 5
// 923.539 us; speedup vs baseline: 12.8480x; 1.1080x over previous
//
#include <hip/hip_runtime.h>
#include <math.h>

#define Bn   32
#define Sn   256
#define En   512
#define Hn   512
#define Wn   512
#define ENCn 1024
#define G4   2048
#define KTOT 1536
#define NC   8      // barrier clusters
#define WPC  32     // WGs per cluster

// ---------------- workspace layout (float offsets) ----------------
#define OFF_BSUM  0L            // [32][256][512]  4194304
#define OFF_U3    4194304L      // [32][256][512]  4194304  (pb overlays first 262144 during pe passes)
#define OFF_PE    8388608L      // [32][257][512]  4210688
#define OFF_WB    12599296L     // [32cb][256kq][64][4] 2097152
#define OFF_W4B   14696448L     // [8cb][128kq][64][4]   262144
#define OFF_GATES 14958592L     // [2kh][32][2048] 131072 (K-half partials)
#define OFF_H     15089664L     // [32][512]       16384
#define OFF_C     15106048L     // [2][32][512]    32768 (ping-pong)
#define OFF_SPART 15138816L     // [32][8][256]    65536
#define OFF_STATE 15204352L     // 8192 ints
// total ~15212544 floats ~= 60.9 MB

// state ints: bond[0..31], last[32..63], nact@64, gcnt@80,
//             bcnt[b]@256+64b, cluster arrive@4096+256c, release@4096+256c+64

// ---------------- coherent (IF-level) access helpers ----------------
__device__ __forceinline__ float aload(const float* p) {
    return __hip_atomic_load(p, __ATOMIC_RELAXED, __HIP_MEMORY_SCOPE_AGENT);
}
__device__ __forceinline__ void astore(float* p, float v) {
    __hip_atomic_store(p, v, __ATOMIC_RELAXED, __HIP_MEMORY_SCOPE_AGENT);
}
__device__ __forceinline__ int aiload(const int* p) {
    return __hip_atomic_load(p, __ATOMIC_RELAXED, __HIP_MEMORY_SCOPE_AGENT);
}
__device__ __forceinline__ void aistore(int* p, int v) {
    __hip_atomic_store(p, v, __ATOMIC_RELAXED, __HIP_MEMORY_SCOPE_AGENT);
}

// ---------------- init ----------------
__global__ void init_kernel(const float* __restrict__ hn0, float* __restrict__ h,
                            float* __restrict__ c, int* __restrict__ state)
{
    int i = blockIdx.x * blockDim.x + threadIdx.x;
    if (i < Bn * Hn) { h[i] = 0.0f; c[i] = hn0[i]; }
    if (i < 8192) state[i] = (i == 64) ? Bn : 0;
}

// ---------------- weight repack ----------------
__global__ void wtrans_kernel(const float* __restrict__ Wx, const float* __restrict__ Wh,
                              const float* __restrict__ W4, float* __restrict__ WB,
                              float* __restrict__ W4B)
{
    int idx = blockIdx.x * 256 + threadIdx.x;
    if (idx < 2097152) {
        const int cc = idx & 3, l = (idx >> 2) & 63, kq = (idx >> 8) & 255, cb = idx >> 16;
        const int k = 4 * kq + cc, j = cb * 64 + l;
        WB[idx] = (k < 512) ? Wx[(long)k * G4 + j] : Wh[(long)(k - 512) * G4 + j];
    }
    if (idx < 262144) {
        const int cc = idx & 3, l = (idx >> 2) & 63, kq = (idx >> 8) & 127, cb = idx >> 15;
        const int k = 4 * kq + cc, j = cb * 64 + l;
        W4B[idx] = W4[(long)k * Wn + j];
    }
}

// ---------------- pe: parallel prefix sums of inp over s ----------------
__global__ void pe1_kernel(const int* __restrict__ wid, const float* __restrict__ emb,
                           float* __restrict__ pb)
{
    const int b = blockIdx.x, blk = blockIdx.y;
    __shared__ int wids[16];
    if (threadIdx.x < 16) wids[threadIdx.x] = wid[b * Sn + blk * 16 + threadIdx.x];
    __syncthreads();
    float a0 = 0.f, a1 = 0.f;
    for (int s = 0; s < 16; ++s) {
        const float* r = emb + (long)wids[s] * En;
        a0 += r[threadIdx.x]; a1 += r[threadIdx.x + 256];
    }
    pb[((long)b * 16 + blk) * En + threadIdx.x] = a0;
    pb[((long)b * 16 + blk) * En + threadIdx.x + 256] = a1;
}

__global__ void pe2_kernel(const int* __restrict__ wid, const float* __restrict__ emb,
                           const float* __restrict__ pb, float* __restrict__ pe)
{
    const int b = blockIdx.x, blk = blockIdx.y;
    __shared__ int wids[16];
    if (threadIdx.x < 16) wids[threadIdx.x] = wid[b * Sn + blk * 16 + threadIdx.x];
    __syncthreads();
    float a0 = 0.f, a1 = 0.f;
    for (int j = 0; j < blk; ++j) {
        a0 += pb[((long)b * 16 + j) * En + threadIdx.x];
        a1 += pb[((long)b * 16 + j) * En + threadIdx.x + 256];
    }
    float* base = pe + (long)b * 257 * En;
    if (blk == 0) { base[threadIdx.x] = 0.f; base[threadIdx.x + 256] = 0.f; }
    for (int s = 0; s < 16; ++s) {
        const float* r = emb + (long)wids[s] * En;
        a0 += r[threadIdx.x]; a1 += r[threadIdx.x + 256];
        float* o = base + (long)(blk * 16 + s + 1) * En;
        o[threadIdx.x] = a0; o[threadIdx.x + 256] = a1;
    }
}

// ---------------- bsum = enc@W1 + emb[wid]@W2 ----------------
__global__ __launch_bounds__(256) void bsum_gemm(
    const float* __restrict__ enc, const int* __restrict__ wid,
    const float* __restrict__ emb, const float* __restrict__ W1,
    const float* __restrict__ W2, float* __restrict__ bsum)
{
    __shared__ float As[16][68];
    __shared__ float Bs[16][68];
    const int tid  = threadIdx.x;
    const int row0 = blockIdx.y * 64;
    const int col0 = blockIdx.x * 64;
    const int tm0  = (tid & 15) * 4;
    const int tn0  = (tid >> 4) * 4;
    const int la_r = tid >> 2;
    const int la_k = (tid & 3) * 4;
    const int lb_k = tid >> 4;
    const int lb_n = (tid & 15) * 4;

    float acc[4][4];
#pragma unroll
    for (int i = 0; i < 4; i++)
#pragma unroll
        for (int j = 0; j < 4; j++) acc[i][j] = 0.0f;

    for (int k0 = 0; k0 < KTOT; k0 += 16) {
        const int gr = row0 + la_r;
        float4 av;
        if (k0 < ENCn) {
            av = *(const float4*)&enc[(long)gr * ENCn + k0 + la_k];
        } else {
            const int wv = wid[gr];
            av = *(const float4*)&emb[(long)wv * En + (k0 - ENCn) + la_k];
        }
        As[la_k + 0][la_r] = av.x;
        As[la_k + 1][la_r] = av.y;
        As[la_k + 2][la_r] = av.z;
        As[la_k + 3][la_r] = av.w;
        float4 bv;
        if (k0 < ENCn) bv = *(const float4*)&W1[(long)(k0 + lb_k) * Wn + col0 + lb_n];
        else           bv = *(const float4*)&W2[(long)(k0 - ENCn + lb_k) * Wn + col0 + lb_n];
        *(float4*)&Bs[lb_k][lb_n] = bv;
        __syncthreads();
#pragma unroll
        for (int kk = 0; kk < 16; kk++) {
            float4 a = *(const float4*)&As[kk][tm0];
            float4 b = *(const float4*)&Bs[kk][tn0];
            acc[0][0] += a.x * b.x; acc[0][1] += a.x * b.y; acc[0][2] += a.x * b.z; acc[0][3] += a.x * b.w;
            acc[1][0] += a.y * b.x; acc[1][1] += a.y * b.y; acc[1][2] += a.y * b.z; acc[1][3] += a.y * b.w;
            acc[2][0] += a.z * b.x; acc[2][1] += a.z * b.y; acc[2][2] += a.z * b.z; acc[2][3] += a.z * b.w;
            acc[3][0] += a.w * b.x; acc[3][1] += a.w * b.y; acc[3][2] += a.w * b.z; acc[3][3] += a.w * b.w;
        }
        __syncthreads();
    }
#pragma unroll
    for (int i = 0; i < 4; i++) {
        float4 o = make_float4(acc[i][0], acc[i][1], acc[i][2], acc[i][3]);
        *(float4*)&bsum[(long)(row0 + tm0 + i) * Wn + col0 + tn0] = o;
    }
}

// ---------------- u3 = emb[wid]@W3 ----------------
__global__ __launch_bounds__(256) void u3_gemm(
    const int* __restrict__ wid, const float* __restrict__ emb,
    const float* __restrict__ W3, float* __restrict__ u3)
{
    __shared__ float As[16][68];
    __shared__ float Bs[16][68];
    const int tid  = threadIdx.x;
    const int row0 = blockIdx.y * 64;
    const int col0 = blockIdx.x * 64;
    const int tm0  = (tid & 15) * 4;
    const int tn0  = (tid >> 4) * 4;
    const int la_r = tid >> 2;
    const int la_k = (tid & 3) * 4;
    const int lb_k = tid >> 4;
    const int lb_n = (tid & 15) * 4;

    float acc[4][4];
#pragma unroll
    for (int i = 0; i < 4; i++)
#pragma unroll
        for (int j = 0; j < 4; j++) acc[i][j] = 0.0f;

    for (int k0 = 0; k0 < 512; k0 += 16) {
        const int gr = row0 + la_r;
        const int wv = wid[gr];
        float4 av = *(const float4*)&emb[(long)wv * En + k0 + la_k];
        As[la_k + 0][la_r] = av.x;
        As[la_k + 1][la_r] = av.y;
        As[la_k + 2][la_r] = av.z;
        As[la_k + 3][la_r] = av.w;
        *(float4*)&Bs[lb_k][lb_n] = *(const float4*)&W3[(long)(k0 + lb_k) * Wn + col0 + lb_n];
        __syncthreads();
#pragma unroll
        for (int kk = 0; kk < 16; kk++) {
            float4 a = *(const float4*)&As[kk][tm0];
            float4 b = *(const float4*)&Bs[kk][tn0];
            acc[0][0] += a.x * b.x; acc[0][1] += a.x * b.y; acc[0][2] += a.x * b.z; acc[0][3] += a.x * b.w;
            acc[1][0] += a.y * b.x; acc[1][1] += a.y * b.y; acc[1][2] += a.y * b.z; acc[1][3] += a.y * b.w;
            acc[2][0] += a.z * b.x; acc[2][1] += a.z * b.y; acc[2][2] += a.z * b.z; acc[2][3] += a.z * b.w;
            acc[3][0] += a.w * b.x; acc[3][1] += a.w * b.y; acc[3][2] += a.w * b.z; acc[3][3] += a.w * b.w;
        }
        __syncthreads();
    }
#pragma unroll
    for (int i = 0; i < 4; i++) {
        float4 o = make_float4(acc[i][0], acc[i][1], acc[i][2], acc[i][3]);
        *(float4*)&u3[(long)(row0 + tm0 + i) * Wn + col0 + tn0] = o;
    }
}

// ---------------- 2-level grid barrier: relaxed coherent atomics, ZERO fences ----------------
__device__ __forceinline__ int gbar(int* st, const int* nact, int wg, int round)
{
    __shared__ int s_done;
    __syncthreads();
    if (threadIdx.x == 0) {
        const int c = wg >> 5;
        int* lc = st + 4096 + 256 * c;
        int* lr = lc + 64;
        int flag = 0;
        bool wait = true;
        int a = __hip_atomic_fetch_add(lc, 1, __ATOMIC_RELAXED, __HIP_MEMORY_SCOPE_AGENT);
        if (a == round * WPC - 1) {
            int g = __hip_atomic_fetch_add(st + 80, 1, __ATOMIC_RELAXED, __HIP_MEMORY_SCOPE_AGENT);
            if (g == round * NC - 1) {
                const int d = (aiload(nact) == 0) ? (1 << 30) : 0;
                flag = round | d;
                for (int k = 0; k < NC; ++k)
                    aistore(st + 4096 + 256 * k + 64, flag);
                wait = false;
            }
        }
        if (wait) {
            for (;;) {
                flag = aiload(lr);
                if ((flag & 0x3FFFFFFF) >= round) break;
                __builtin_amdgcn_s_sleep(1);
            }
        }
        s_done = (flag >> 30) & 1;
    }
    __syncthreads();
    return s_done;
}

// ---------------- persistent decode: 256 WGs x 256 thr, LDS-resident P1 weights ----------------
// P1: wg = (cb1 = wg&31 [64 cols of 2048], kh = (wg>>5)&1 [K-half], bg = wg>>6 [8 batches])
//     gates partial[kh][b][col] = (x|h)[K-half] @ WB-slice   (weights live in LDS)
// P2: wg = (b2 = wg>>3, cb2 = wg&7): LSTM(sum 2 partials) -> u4 -> scores -> argmax -> state
__global__ __launch_bounds__(256) void decode_kernel(
    const float* __restrict__ bias, const float* __restrict__ vt1,
    const float* __restrict__ bsum, const float* __restrict__ u3,
    const float* __restrict__ pe,   const float* __restrict__ WB,
    const float* __restrict__ W4B,  float* __restrict__ gpart,
    float* __restrict__ hbuf, float* __restrict__ cbuf,
    float* __restrict__ spart,
    int* __restrict__ state, float* __restrict__ out)
{
    __shared__ __align__(16) float wlds[32768];   // 128 KB weight slice
    __shared__ __align__(16) float sx[4096];      // P1 stage / P2 work
    __shared__ __align__(16) float sred[2048];    // P1 cross-wave reduce
    __shared__ float s_svt[64];
    __shared__ float s_wv[4];
    __shared__ int   s_wi[4];
    __shared__ int   s_last;
    __shared__ int   s_bd[8], s_ls[8];

    const int wg   = blockIdx.x;
    const int tid  = threadIdx.x;
    const int lane = tid & 63;
    const int wv   = tid >> 6;

    int* bond = state;
    int* last = state + 32;
    int* nact = state + 64;

    const int cb1 = wg & 31;
    const int kh  = (wg >> 5) & 1;
    const int bg  = wg >> 6;          // 0..3, batches bg*8..bg*8+7
    const int b2  = wg >> 3;
    const int cb2 = wg & 7;
    const float4* W4B4 = (const float4*)W4B;
    float4* wlds4 = (float4*)wlds;
    float4* sx4   = (float4*)sx;

    // preload 128 KB weight slice: WB4[(cb1*256 + kh*128 + kq)*64 + lane], kq 0..127
    {
        const float4* src = (const float4*)WB + ((long)cb1 * 256 + kh * 128) * 64;
        for (int i = tid; i < 8192; i += 256) wlds4[i] = src[i];
    }
    if (tid < 64) s_svt[tid] = vt1[cb2 * 64 + tid];

    int myround = 0;

    for (int step = 0; step < Sn; ++step) {
        const float* cold = cbuf + (step & 1) * (Bn * Hn);
        float*       cnew = cbuf + ((step + 1) & 1) * (Bn * Hn);

        // ======== P1 ========
        if (tid < 8) {
            s_bd[tid] = aiload(&bond[bg * 8 + tid]);
            s_ls[tid] = aiload(&last[bg * 8 + tid]);
        }
        __syncthreads();
        // stage 8 batches x 512 (x if kh==0 else h)
        for (int idx = tid; idx < 4096; idx += 256) {
            const int bq = idx >> 9, k = idx & 511;
            const int b  = bg * 8 + bq;
            float v;
            if (kh == 0) {
                const int bd = s_bd[bq], ls = s_ls[bq];
                const float inv = 1.0f / (float)max(bd - ls, 1);
                v = (pe[((long)b * 257 + bd) * En + k] - pe[((long)b * 257 + ls) * En + k]) * inv;
            } else {
                v = aload(&hbuf[b * Hn + k]);
            }
            sx[idx] = v;                 // [bq][512]
        }
        __syncthreads();
        // GEMV from LDS: wave wv owns K-chunk 128; lane = col
        {
            float acc[8] = {0.f,0.f,0.f,0.f,0.f,0.f,0.f,0.f};
            const float4* wl = wlds4 + (wv * 32) * 64 + lane;
#pragma unroll 8
            for (int kq = 0; kq < 32; ++kq) {
                const float4 w = wl[kq * 64];
                const int kb = wv * 32 + kq;
#pragma unroll
                for (int bq = 0; bq < 8; ++bq) {
                    const float4 xv = sx4[bq * 128 + kb];
                    acc[bq] += w.x * xv.x + w.y * xv.y + w.z * xv.z + w.w * xv.w;
                }
            }
#pragma unroll
            for (int bq = 0; bq < 8; ++bq)
                sred[wv * 512 + bq * 64 + lane] = acc[bq];
        }
        __syncthreads();
#pragma unroll
        for (int o = tid; o < 512; o += 256) {
            const int bq = o >> 6;
            if (s_bd[bq] < Sn) {
                const float s = sred[o] + sred[512 + o] + sred[1024 + o] + sred[1536 + o];
                astore(&gpart[((long)(kh * Bn) + bg * 8 + bq) * G4 + cb1 * 64 + (o & 63)], s);
            }
        }
        gbar(state, nact, wg, 2 * step + 1);

        // ======== P2 ========
        const int bd = aiload(&bond[b2]);
        if (bd < Sn) {
            ++myround;
            const float* gp0 = gpart + (long)b2 * G4;
            const float* gp1 = gpart + (long)(Bn + b2) * G4;
            for (int j = tid; j < Hn; j += 256) {
                const float ig = aload(&gp0[j])        + aload(&gp1[j])        + bias[j];
                const float fg = aload(&gp0[512 + j])  + aload(&gp1[512 + j])  + bias[512 + j];
                const float gg = aload(&gp0[1024 + j]) + aload(&gp1[1024 + j]) + bias[1024 + j];
                const float og = aload(&gp0[1536 + j]) + aload(&gp1[1536 + j]) + bias[1536 + j];
                const float co = aload(&cold[b2 * Hn + j]);
                const float sf  = 1.f / (1.f + expf(-fg));
                const float sig = 1.f / (1.f + expf(-ig));
                const float so  = 1.f / (1.f + expf(-og));
                const float cn  = sf * co + sig * tanhf(gg);
                const float h2  = so * tanhf(cn);
                sx[j] = h2;
                if (cb2 == 0) { astore(&hbuf[b2 * Hn + j], h2); astore(&cnew[b2 * Hn + j], cn); }
            }
            __syncthreads();
            // u4 slice (64 cols), wave-split K
            {
                float acc = 0.f;
                const float4* wrow = W4B4 + ((long)cb2 * 128 + wv * 32) * 64 + lane;
#pragma unroll 8
                for (int kq = 0; kq < 32; ++kq) {
                    const float4 w  = wrow[(long)kq * 64];
                    const float4 xv = sx4[wv * 32 + kq];
                    acc += w.x * xv.x + w.y * xv.y + w.z * xv.z + w.w * xv.w;
                }
                sx[512 + wv * 64 + lane] = acc;
            }
            __syncthreads();
            if (tid < 64) {
                const float* u3row = u3 + ((long)b2 * Sn + bd) * Wn + cb2 * 64;
                sx[768 + tid] = sx[512 + tid] + sx[576 + tid] + sx[640 + tid]
                              + sx[704 + tid] + u3row[tid];
            }
            __syncthreads();
            // partial scores: thread tid = row p
            if (tid >= bd) {
                const float* row = bsum + ((long)b2 * Sn + tid) * Wn + cb2 * 64;
                float a = 0.f;
#pragma unroll 8
                for (int i = 0; i < 64; ++i)
                    a += tanhf(row[i] + sx[768 + i]) * s_svt[i];
                astore(&spart[((long)b2 * 8 + cb2) * 256 + tid], a);
            }
            __syncthreads();
            if (tid == 0) {
                int o = __hip_atomic_fetch_add(state + 256 + 64 * b2, 1,
                                               __ATOMIC_RELAXED, __HIP_MEMORY_SCOPE_AGENT);
                s_last = (o == myround * 8 - 1);
            }
            __syncthreads();
            if (s_last) {
                float v = -3.402823e38f; int vi = Sn;
                if (tid >= bd) {
                    const float* sp = spart + (long)b2 * 8 * 256 + tid;
                    float s = 0.f;
#pragma unroll
                    for (int k = 0; k < 8; ++k) s += aload(&sp[k * 256]);
                    v = s; vi = tid;
                }
#pragma unroll
                for (int off = 32; off; off >>= 1) {
                    const float v2 = __shfl_xor(v, off, 64);
                    const int   i2 = __shfl_xor(vi, off, 64);
                    if (v2 > v || (v2 == v && i2 < vi)) { v = v2; vi = i2; }
                }
                if (lane == 0) { s_wv[wv] = v; s_wi[wv] = vi; }
                __syncthreads();
                if (tid == 0) {
                    float bv = s_wv[0]; int bi = s_wi[0];
#pragma unroll
                    for (int k = 1; k < 4; ++k)
                        if (s_wv[k] > bv || (s_wv[k] == bv && s_wi[k] < bi)) { bv = s_wv[k]; bi = s_wi[k]; }
                    const int nb2 = (bi > bd) ? bi : bd + 1;
                    if (nb2 < Sn) out[nb2 * Bn + b2] = 1.0f;
                    else __hip_atomic_fetch_add(nact, -1, __ATOMIC_RELAXED, __HIP_MEMORY_SCOPE_AGENT);
                    aistore(&last[b2], bd);
                    aistore(&bond[b2], nb2);
                }
            }
        }
        if (gbar(state, nact, wg, 2 * step + 2)) break;
    }
}

extern "C" void kernel_launch(void* const* d_in, const int* in_sizes, int n_in,
                              void* d_out, int out_size, void* d_ws, size_t ws_size,
                              hipStream_t stream)
{
    const int*   wid  = (const int*)d_in[0];
    const float* enc  = (const float*)d_in[1];
    const float* hn0  = (const float*)d_in[2];
    const float* emb  = (const float*)d_in[3];
    // d_in[4] chunk_emb : unused (uniform score shift, argmax-invariant)
    const float* W1   = (const float*)d_in[5];
    const float* W2   = (const float*)d_in[6];
    const float* W3   = (const float*)d_in[7];
    const float* W4   = (const float*)d_in[8];
    const float* vt1  = (const float*)d_in[9];
    // d_in[10] vt2 : unused
    const float* Wx   = (const float*)d_in[11];
    const float* Wh   = (const float*)d_in[12];
    const float* bias = (const float*)d_in[13];

    float* ws    = (float*)d_ws;
    float* bsum  = ws + OFF_BSUM;
    float* u3    = ws + OFF_U3;
    float* pb    = ws + OFF_U3;       // overlay: used only before u3_gemm
    float* pe    = ws + OFF_PE;
    float* WB    = ws + OFF_WB;
    float* W4B   = ws + OFF_W4B;
    float* gpart = ws + OFF_GATES;
    float* h     = ws + OFF_H;
    float* c     = ws + OFF_C;
    float* spart = ws + OFF_SPART;
    int*   state = (int*)(ws + OFF_STATE);
    float* out   = (float*)d_out;

    hipMemsetAsync(d_out, 0, (size_t)Sn * Bn * sizeof(float), stream);
    hipLaunchKernelGGL(init_kernel, dim3(64), dim3(256), 0, stream, hn0, h, c, state);
    hipLaunchKernelGGL(wtrans_kernel, dim3(8192), dim3(256), 0, stream, Wx, Wh, W4, WB, W4B);
    hipLaunchKernelGGL(pe1_kernel, dim3(32, 16), dim3(256), 0, stream, wid, emb, pb);
    hipLaunchKernelGGL(pe2_kernel, dim3(32, 16), dim3(256), 0, stream, wid, emb, pb, pe);
    hipLaunchKernelGGL(u3_gemm, dim3(8, 128), dim3(256), 0, stream, wid, emb, W3, u3);
    hipLaunchKernelGGL(bsum_gemm, dim3(8, 128), dim3(256), 0, stream, enc, wid, emb, W1, W2, bsum);

    void* args[] = { (void*)&bias, (void*)&vt1, (void*)&bsum, (void*)&u3, (void*)&pe,
                     (void*)&WB, (void*)&W4B, (void*)&gpart, (void*)&h, (void*)&c,
                     (void*)&spart, (void*)&state, (void*)&out };
    hipLaunchCooperativeKernel((void*)decode_kernel, dim3(256), dim3(256), args, 0, stream);
}

// Round 6
// 865.733 us; speedup vs baseline: 13.7059x; 1.0668x over previous
//
#include <hip/hip_runtime.h>
#include <math.h>

#define Bn   32
#define Sn   256
#define En   512
#define Hn   512
#define Wn   512
#define ENCn 1024
#define G4   2048
#define KTOT 1536

// ---------------- workspace layout (float offsets) ----------------
#define OFF_BSUM  0L            // [32][256][512]  4194304
#define OFF_U3    4194304L      // [32][256][512]  4194304  (pb overlays first 262144 during pe passes)
#define OFF_PE    8388608L      // [32][257][512]  4210688
#define OFF_WB    12599296L     // [32cb][256kq][64][4] 2097152
#define OFF_W4B   14696448L     // [8cb][128kq][64][4]   262144
#define OFF_GATES 14958592L     // [2kh][32][2048] 131072 (K-half partials)
#define OFF_H     15089664L     // [32][512]       16384
#define OFF_C     15106048L     // [2][32][512]    32768 (ping-pong by per-batch active-step parity)
#define OFF_SPART 15138816L     // [32][8][256]    65536
#define OFF_STATE 15204352L     // 8192 ints
// total ~15212544 floats ~= 60.9 MB

// state ints (each counter on its own 64B line):
//   gcnt[b]  @ 16*b          (P1 gate-slice arrivals, +64 per step)
//   scnt[b]  @ 512 + 16*b    (P2 spart arrivals, +8 per active step)
//   nact     @ 1024
//   packed64 @ 1536 + 16*b   (u64: epoch[0:16] | bond[16:32] | last[32:48])

// ---------------- coherent (IF-level) access helpers ----------------
__device__ __forceinline__ float aload(const float* p) {
    return __hip_atomic_load(p, __ATOMIC_RELAXED, __HIP_MEMORY_SCOPE_AGENT);
}
__device__ __forceinline__ void astore(float* p, float v) {
    __hip_atomic_store(p, v, __ATOMIC_RELAXED, __HIP_MEMORY_SCOPE_AGENT);
}
__device__ __forceinline__ int aiload(const int* p) {
    return __hip_atomic_load(p, __ATOMIC_RELAXED, __HIP_MEMORY_SCOPE_AGENT);
}
__device__ __forceinline__ unsigned long long aload64(const unsigned long long* p) {
    return __hip_atomic_load(p, __ATOMIC_RELAXED, __HIP_MEMORY_SCOPE_AGENT);
}
__device__ __forceinline__ void astore64(unsigned long long* p, unsigned long long v) {
    __hip_atomic_store(p, v, __ATOMIC_RELAXED, __HIP_MEMORY_SCOPE_AGENT);
}

// ---------------- init ----------------
__global__ void init_kernel(const float* __restrict__ hn0, float* __restrict__ h,
                            float* __restrict__ c, int* __restrict__ state)
{
    int i = blockIdx.x * blockDim.x + threadIdx.x;
    if (i < Bn * Hn) { h[i] = 0.0f; c[i] = hn0[i]; }
    if (i < 8192) state[i] = (i == 1024) ? Bn : 0;
}

// ---------------- weight repack ----------------
__global__ void wtrans_kernel(const float* __restrict__ Wx, const float* __restrict__ Wh,
                              const float* __restrict__ W4, float* __restrict__ WB,
                              float* __restrict__ W4B)
{
    int idx = blockIdx.x * 256 + threadIdx.x;
    if (idx < 2097152) {
        const int cc = idx & 3, l = (idx >> 2) & 63, kq = (idx >> 8) & 255, cb = idx >> 16;
        const int k = 4 * kq + cc, j = cb * 64 + l;
        WB[idx] = (k < 512) ? Wx[(long)k * G4 + j] : Wh[(long)(k - 512) * G4 + j];
    }
    if (idx < 262144) {
        const int cc = idx & 3, l = (idx >> 2) & 63, kq = (idx >> 8) & 127, cb = idx >> 15;
        const int k = 4 * kq + cc, j = cb * 64 + l;
        W4B[idx] = W4[(long)k * Wn + j];
    }
}

// ---------------- pe: parallel prefix sums of inp over s ----------------
__global__ void pe1_kernel(const int* __restrict__ wid, const float* __restrict__ emb,
                           float* __restrict__ pb)
{
    const int b = blockIdx.x, blk = blockIdx.y;
    __shared__ int wids[16];
    if (threadIdx.x < 16) wids[threadIdx.x] = wid[b * Sn + blk * 16 + threadIdx.x];
    __syncthreads();
    float a0 = 0.f, a1 = 0.f;
    for (int s = 0; s < 16; ++s) {
        const float* r = emb + (long)wids[s] * En;
        a0 += r[threadIdx.x]; a1 += r[threadIdx.x + 256];
    }
    pb[((long)b * 16 + blk) * En + threadIdx.x] = a0;
    pb[((long)b * 16 + blk) * En + threadIdx.x + 256] = a1;
}

__global__ void pe2_kernel(const int* __restrict__ wid, const float* __restrict__ emb,
                           const float* __restrict__ pb, float* __restrict__ pe)
{
    const int b = blockIdx.x, blk = blockIdx.y;
    __shared__ int wids[16];
    if (threadIdx.x < 16) wids[threadIdx.x] = wid[b * Sn + blk * 16 + threadIdx.x];
    __syncthreads();
    float a0 = 0.f, a1 = 0.f;
    for (int j = 0; j < blk; ++j) {
        a0 += pb[((long)b * 16 + j) * En + threadIdx.x];
        a1 += pb[((long)b * 16 + j) * En + threadIdx.x + 256];
    }
    float* base = pe + (long)b * 257 * En;
    if (blk == 0) { base[threadIdx.x] = 0.f; base[threadIdx.x + 256] = 0.f; }
    for (int s = 0; s < 16; ++s) {
        const float* r = emb + (long)wids[s] * En;
        a0 += r[threadIdx.x]; a1 += r[threadIdx.x + 256];
        float* o = base + (long)(blk * 16 + s + 1) * En;
        o[threadIdx.x] = a0; o[threadIdx.x + 256] = a1;
    }
}

// ---------------- bsum = enc@W1 + emb[wid]@W2 ----------------
__global__ __launch_bounds__(256) void bsum_gemm(
    const float* __restrict__ enc, const int* __restrict__ wid,
    const float* __restrict__ emb, const float* __restrict__ W1,
    const float* __restrict__ W2, float* __restrict__ bsum)
{
    __shared__ float As[16][68];
    __shared__ float Bs[16][68];
    const int tid  = threadIdx.x;
    const int row0 = blockIdx.y * 64;
    const int col0 = blockIdx.x * 64;
    const int tm0  = (tid & 15) * 4;
    const int tn0  = (tid >> 4) * 4;
    const int la_r = tid >> 2;
    const int la_k = (tid & 3) * 4;
    const int lb_k = tid >> 4;
    const int lb_n = (tid & 15) * 4;

    float acc[4][4];
#pragma unroll
    for (int i = 0; i < 4; i++)
#pragma unroll
        for (int j = 0; j < 4; j++) acc[i][j] = 0.0f;

    for (int k0 = 0; k0 < KTOT; k0 += 16) {
        const int gr = row0 + la_r;
        float4 av;
        if (k0 < ENCn) {
            av = *(const float4*)&enc[(long)gr * ENCn + k0 + la_k];
        } else {
            const int wv = wid[gr];
            av = *(const float4*)&emb[(long)wv * En + (k0 - ENCn) + la_k];
        }
        As[la_k + 0][la_r] = av.x;
        As[la_k + 1][la_r] = av.y;
        As[la_k + 2][la_r] = av.z;
        As[la_k + 3][la_r] = av.w;
        float4 bv;
        if (k0 < ENCn) bv = *(const float4*)&W1[(long)(k0 + lb_k) * Wn + col0 + lb_n];
        else           bv = *(const float4*)&W2[(long)(k0 - ENCn + lb_k) * Wn + col0 + lb_n];
        *(float4*)&Bs[lb_k][lb_n] = bv;
        __syncthreads();
#pragma unroll
        for (int kk = 0; kk < 16; kk++) {
            float4 a = *(const float4*)&As[kk][tm0];
            float4 b = *(const float4*)&Bs[kk][tn0];
            acc[0][0] += a.x * b.x; acc[0][1] += a.x * b.y; acc[0][2] += a.x * b.z; acc[0][3] += a.x * b.w;
            acc[1][0] += a.y * b.x; acc[1][1] += a.y * b.y; acc[1][2] += a.y * b.z; acc[1][3] += a.y * b.w;
            acc[2][0] += a.z * b.x; acc[2][1] += a.z * b.y; acc[2][2] += a.z * b.z; acc[2][3] += a.z * b.w;
            acc[3][0] += a.w * b.x; acc[3][1] += a.w * b.y; acc[3][2] += a.w * b.z; acc[3][3] += a.w * b.w;
        }
        __syncthreads();
    }
#pragma unroll
    for (int i = 0; i < 4; i++) {
        float4 o = make_float4(acc[i][0], acc[i][1], acc[i][2], acc[i][3]);
        *(float4*)&bsum[(long)(row0 + tm0 + i) * Wn + col0 + tn0] = o;
    }
}

// ---------------- u3 = emb[wid]@W3 ----------------
__global__ __launch_bounds__(256) void u3_gemm(
    const int* __restrict__ wid, const float* __restrict__ emb,
    const float* __restrict__ W3, float* __restrict__ u3)
{
    __shared__ float As[16][68];
    __shared__ float Bs[16][68];
    const int tid  = threadIdx.x;
    const int row0 = blockIdx.y * 64;
    const int col0 = blockIdx.x * 64;
    const int tm0  = (tid & 15) * 4;
    const int tn0  = (tid >> 4) * 4;
    const int la_r = tid >> 2;
    const int la_k = (tid & 3) * 4;
    const int lb_k = tid >> 4;
    const int lb_n = (tid & 15) * 4;

    float acc[4][4];
#pragma unroll
    for (int i = 0; i < 4; i++)
#pragma unroll
        for (int j = 0; j < 4; j++) acc[i][j] = 0.0f;

    for (int k0 = 0; k0 < 512; k0 += 16) {
        const int gr = row0 + la_r;
        const int wv = wid[gr];
        float4 av = *(const float4*)&emb[(long)wv * En + k0 + la_k];
        As[la_k + 0][la_r] = av.x;
        As[la_k + 1][la_r] = av.y;
        As[la_k + 2][la_r] = av.z;
        As[la_k + 3][la_r] = av.w;
        *(float4*)&Bs[lb_k][lb_n] = *(const float4*)&W3[(long)(k0 + lb_k) * Wn + col0 + lb_n];
        __syncthreads();
#pragma unroll
        for (int kk = 0; kk < 16; kk++) {
            float4 a = *(const float4*)&As[kk][tm0];
            float4 b = *(const float4*)&Bs[kk][tn0];
            acc[0][0] += a.x * b.x; acc[0][1] += a.x * b.y; acc[0][2] += a.x * b.z; acc[0][3] += a.x * b.w;
            acc[1][0] += a.y * b.x; acc[1][1] += a.y * b.y; acc[1][2] += a.y * b.z; acc[1][3] += a.y * b.w;
            acc[2][0] += a.z * b.x; acc[2][1] += a.z * b.y; acc[2][2] += a.z * b.z; acc[2][3] += a.z * b.w;
            acc[3][0] += a.w * b.x; acc[3][1] += a.w * b.y; acc[3][2] += a.w * b.z; acc[3][3] += a.w * b.w;
        }
        __syncthreads();
    }
#pragma unroll
    for (int i = 0; i < 4; i++) {
        float4 o = make_float4(acc[i][0], acc[i][1], acc[i][2], acc[i][3]);
        *(float4*)&u3[(long)(row0 + tm0 + i) * Wn + col0 + tn0] = o;
    }
}

// ---------------- persistent decode: 256 WGs x 256 thr, flag-based dataflow (NO global barrier) ----------------
// P1: wg = (cb1 = wg&31, kh = (wg>>5)&1, bg = wg>>6): gates partial from LDS-resident weights.
//     waits: packed64[b].epoch >= t-1 (or bond>=Sn) for its 8 batches.  publishes: gcnt[b] += 1 (x64 WGs).
// P2: wg = (b2 = wg>>3, cb2 = wg&7): waits gcnt[b2] >= 64*t; LSTM+u4+scores -> spart; scnt arrive;
//     last arriver sums, argmaxes, publishes packed64[b2] = {epoch=t, bond, last}.
__global__ __launch_bounds__(256) void decode_kernel(
    const float* __restrict__ bias, const float* __restrict__ vt1,
    const float* __restrict__ bsum, const float* __restrict__ u3,
    const float* __restrict__ pe,   const float* __restrict__ WB,
    const float* __restrict__ W4B,  float* __restrict__ gpart,
    float* __restrict__ hbuf, float* __restrict__ cbuf,
    float* __restrict__ spart,
    int* __restrict__ state, float* __restrict__ out)
{
    __shared__ __align__(16) float wlds[32768];   // 128 KB weight slice
    __shared__ __align__(16) float sx[4096];      // P1 stage / P2 work
    __shared__ __align__(16) float sred[2048];    // P1 cross-wave reduce
    __shared__ float s_svt[64];
    __shared__ float s_wv[4];
    __shared__ int   s_wi[4];
    __shared__ int   s_last;
    __shared__ int   s_bd[8], s_ls[8];
    __shared__ int   s_exit;

    const int wg   = blockIdx.x;
    const int tid  = threadIdx.x;
    const int lane = tid & 63;
    const int wv   = tid >> 6;

    int* gcnt = state;                 // 16*b
    int* scnt = state + 512;           // 16*b
    int* nact = state + 1024;
    unsigned long long* s64b = (unsigned long long*)(state + 1536);  // 8*b (u64 units)

    const int cb1 = wg & 31;
    const int kh  = (wg >> 5) & 1;
    const int bg  = wg >> 6;          // 0..3, batches bg*8..bg*8+7
    const int b2  = wg >> 3;
    const int cb2 = wg & 7;
    const int bq2 = (wg >> 3) & 7;    // b2's index within bg's set
    const float4* W4B4 = (const float4*)W4B;
    float4* wlds4 = (float4*)wlds;
    float4* sx4   = (float4*)sx;

    // preload 128 KB weight slice
    {
        const float4* src = (const float4*)WB + ((long)cb1 * 256 + kh * 128) * 64;
        for (int i = tid; i < 8192; i += 256) wlds4[i] = src[i];
    }
    if (tid < 64) s_svt[tid] = vt1[cb2 * 64 + tid];

    int a_b = 0;   // active-step count of my P2 batch

    for (int t = 1; t <= Sn; ++t) {
        // ======== P1 wait: epochs of my 8 batches (lanes 0..7 in parallel) ========
        if (tid < 64) {
            const bool isb = tid < 8;
            const unsigned long long* sp = s64b + 8 * (bg * 8 + (tid & 7));
            for (;;) {
                unsigned long long pk = isb ? aload64(sp) : 0ULL;
                const int ep = (int)(pk & 0xffffu);
                const int bd = (int)((pk >> 16) & 0xffffu);
                const bool ok = !isb || (ep >= t - 1) || (bd >= Sn);
                int ex = 0;
                if (tid == 8) ex = (aiload(nact) == 0);
                const unsigned long long bal  = __ballot(ok);
                const unsigned long long balx = __ballot(ex != 0);
                if (((bal & 0xffULL) == 0xffULL) || balx) {
                    if (isb) { s_bd[tid] = bd; s_ls[tid] = (int)((pk >> 32) & 0xffffu); }
                    if (tid == 0) s_exit = (balx != 0ULL);
                    break;
                }
                __builtin_amdgcn_s_sleep(1);
            }
        }
        __syncthreads();
        if (s_exit) break;

        int anyact = 0;
#pragma unroll
        for (int q = 0; q < 8; ++q) anyact |= (s_bd[q] < Sn);

        if (anyact) {
            // stage 8 batches x 512 (x if kh==0 else h); zeros for done batches
            for (int idx = tid; idx < 4096; idx += 256) {
                const int bq = idx >> 9, k = idx & 511;
                const int b  = bg * 8 + bq;
                float v = 0.f;
                if (s_bd[bq] < Sn) {
                    if (kh == 0) {
                        const int bd = s_bd[bq], ls = s_ls[bq];
                        const float inv = 1.0f / (float)max(bd - ls, 1);
                        v = (pe[((long)b * 257 + bd) * En + k] - pe[((long)b * 257 + ls) * En + k]) * inv;
                    } else {
                        v = aload(&hbuf[b * Hn + k]);
                    }
                }
                sx[idx] = v;                 // [bq][512]
            }
            __syncthreads();
            // GEMV from LDS
            {
                float acc[8] = {0.f,0.f,0.f,0.f,0.f,0.f,0.f,0.f};
                const float4* wl = wlds4 + (wv * 32) * 64 + lane;
#pragma unroll 8
                for (int kq = 0; kq < 32; ++kq) {
                    const float4 w = wl[kq * 64];
                    const int kb = wv * 32 + kq;
#pragma unroll
                    for (int bq = 0; bq < 8; ++bq) {
                        const float4 xv = sx4[bq * 128 + kb];
                        acc[bq] += w.x * xv.x + w.y * xv.y + w.z * xv.z + w.w * xv.w;
                    }
                }
#pragma unroll
                for (int bq = 0; bq < 8; ++bq)
                    sred[wv * 512 + bq * 64 + lane] = acc[bq];
            }
            __syncthreads();
#pragma unroll
            for (int o = tid; o < 512; o += 256) {
                const int bq = o >> 6;
                if (s_bd[bq] < Sn) {
                    const float s = sred[o] + sred[512 + o] + sred[1024 + o] + sred[1536 + o];
                    astore(&gpart[((long)(kh * Bn) + bg * 8 + bq) * G4 + cb1 * 64 + (o & 63)], s);
                }
            }
            __syncthreads();   // drain gpart stores before arrivals
        }
        // arrivals: 8 parallel lanes, one per batch (unconditional: target is 64*t)
        if (tid < 8)
            __hip_atomic_fetch_add(&gcnt[16 * (bg * 8 + tid)], 1,
                                   __ATOMIC_RELAXED, __HIP_MEMORY_SCOPE_AGENT);

        // ======== P2 ========
        const int bd = s_bd[bq2];
        if (bd < Sn) {
            ++a_b;
            const float* cold = cbuf + ((a_b - 1) & 1) * (Bn * Hn);
            float*       cnew = cbuf + (a_b & 1) * (Bn * Hn);
            // wait for all 64 gate slices of my batch
            if (tid == 0) {
                while (aiload(&gcnt[16 * b2]) < 64 * t) __builtin_amdgcn_s_sleep(1);
            }
            __syncthreads();
            const float* gp0 = gpart + (long)b2 * G4;
            const float* gp1 = gpart + (long)(Bn + b2) * G4;
            for (int j = tid; j < Hn; j += 256) {
                const float ig = aload(&gp0[j])        + aload(&gp1[j])        + bias[j];
                const float fg = aload(&gp0[512 + j])  + aload(&gp1[512 + j])  + bias[512 + j];
                const float gg = aload(&gp0[1024 + j]) + aload(&gp1[1024 + j]) + bias[1024 + j];
                const float og = aload(&gp0[1536 + j]) + aload(&gp1[1536 + j]) + bias[1536 + j];
                const float co = aload(&cold[b2 * Hn + j]);
                const float sf  = 1.f / (1.f + expf(-fg));
                const float sig = 1.f / (1.f + expf(-ig));
                const float so  = 1.f / (1.f + expf(-og));
                const float cn  = sf * co + sig * tanhf(gg);
                const float h2  = so * tanhf(cn);
                sx[j] = h2;
                if (cb2 == 0) { astore(&hbuf[b2 * Hn + j], h2); astore(&cnew[b2 * Hn + j], cn); }
            }
            __syncthreads();
            // u4 slice (64 cols), wave-split K
            {
                float acc = 0.f;
                const float4* wrow = W4B4 + ((long)cb2 * 128 + wv * 32) * 64 + lane;
#pragma unroll 8
                for (int kq = 0; kq < 32; ++kq) {
                    const float4 w  = wrow[(long)kq * 64];
                    const float4 xv = sx4[wv * 32 + kq];
                    acc += w.x * xv.x + w.y * xv.y + w.z * xv.z + w.w * xv.w;
                }
                sx[512 + wv * 64 + lane] = acc;
            }
            __syncthreads();
            if (tid < 64) {
                const float* u3row = u3 + ((long)b2 * Sn + bd) * Wn + cb2 * 64;
                sx[768 + tid] = sx[512 + tid] + sx[576 + tid] + sx[640 + tid]
                              + sx[704 + tid] + u3row[tid];
            }
            __syncthreads();
            // partial scores: thread tid = row p
            if (tid >= bd) {
                const float* row = bsum + ((long)b2 * Sn + tid) * Wn + cb2 * 64;
                float a = 0.f;
#pragma unroll 8
                for (int i = 0; i < 64; ++i)
                    a += tanhf(row[i] + sx[768 + i]) * s_svt[i];
                astore(&spart[((long)b2 * 8 + cb2) * 256 + tid], a);
            }
            __syncthreads();                 // drain spart stores
            if (tid == 0) {
                int o = __hip_atomic_fetch_add(&scnt[16 * b2], 1,
                                               __ATOMIC_RELAXED, __HIP_MEMORY_SCOPE_AGENT);
                s_last = (o == 8 * a_b - 1);
            }
            __syncthreads();
            if (s_last) {
                float v = -3.402823e38f; int vi = Sn;
                if (tid >= bd) {
                    const float* sp = spart + (long)b2 * 8 * 256 + tid;
                    float s = 0.f;
#pragma unroll
                    for (int k = 0; k < 8; ++k) s += aload(&sp[k * 256]);
                    v = s; vi = tid;
                }
#pragma unroll
                for (int off = 32; off; off >>= 1) {
                    const float v2 = __shfl_xor(v, off, 64);
                    const int   i2 = __shfl_xor(vi, off, 64);
                    if (v2 > v || (v2 == v && i2 < vi)) { v = v2; vi = i2; }
                }
                if (lane == 0) { s_wv[wv] = v; s_wi[wv] = vi; }
                __syncthreads();
                if (tid == 0) {
                    float bv = s_wv[0]; int bi = s_wi[0];
#pragma unroll
                    for (int k = 1; k < 4; ++k)
                        if (s_wv[k] > bv || (s_wv[k] == bv && s_wi[k] < bi)) { bv = s_wv[k]; bi = s_wi[k]; }
                    const int nb2 = (bi > bd) ? bi : bd + 1;
                    if (nb2 < Sn) out[nb2 * Bn + b2] = 1.0f;
                    else __hip_atomic_fetch_add(nact, -1, __ATOMIC_RELAXED, __HIP_MEMORY_SCOPE_AGENT);
                    const unsigned long long pk =
                        (unsigned long long)(unsigned)t |
                        ((unsigned long long)(unsigned)nb2 << 16) |
                        ((unsigned long long)(unsigned)bd  << 32);
                    astore64(&s64b[8 * b2], pk);
                }
            }
        }
    }
}

extern "C" void kernel_launch(void* const* d_in, const int* in_sizes, int n_in,
                              void* d_out, int out_size, void* d_ws, size_t ws_size,
                              hipStream_t stream)
{
    const int*   wid  = (const int*)d_in[0];
    const float* enc  = (const float*)d_in[1];
    const float* hn0  = (const float*)d_in[2];
    const float* emb  = (const float*)d_in[3];
    // d_in[4] chunk_emb : unused (uniform score shift, argmax-invariant)
    const float* W1   = (const float*)d_in[5];
    const float* W2   = (const float*)d_in[6];
    const float* W3   = (const float*)d_in[7];
    const float* W4   = (const float*)d_in[8];
    const float* vt1  = (const float*)d_in[9];
    // d_in[10] vt2 : unused
    const float* Wx   = (const float*)d_in[11];
    const float* Wh   = (const float*)d_in[12];
    const float* bias = (const float*)d_in[13];

    float* ws    = (float*)d_ws;
    float* bsum  = ws + OFF_BSUM;
    float* u3    = ws + OFF_U3;
    float* pb    = ws + OFF_U3;       // overlay: used only before u3_gemm
    float* pe    = ws + OFF_PE;
    float* WB    = ws + OFF_WB;
    float* W4B   = ws + OFF_W4B;
    float* gpart = ws + OFF_GATES;
    float* h     = ws + OFF_H;
    float* c     = ws + OFF_C;
    float* spart = ws + OFF_SPART;
    int*   state = (int*)(ws + OFF_STATE);
    float* out   = (float*)d_out;

    hipMemsetAsync(d_out, 0, (size_t)Sn * Bn * sizeof(float), stream);
    hipLaunchKernelGGL(init_kernel, dim3(64), dim3(256), 0, stream, hn0, h, c, state);
    hipLaunchKernelGGL(wtrans_kernel, dim3(8192), dim3(256), 0, stream, Wx, Wh, W4, WB, W4B);
    hipLaunchKernelGGL(pe1_kernel, dim3(32, 16), dim3(256), 0, stream, wid, emb, pb);
    hipLaunchKernelGGL(pe2_kernel, dim3(32, 16), dim3(256), 0, stream, wid, emb, pb, pe);
    hipLaunchKernelGGL(u3_gemm, dim3(8, 128), dim3(256), 0, stream, wid, emb, W3, u3);
    hipLaunchKernelGGL(bsum_gemm, dim3(8, 128), dim3(256), 0, stream, enc, wid, emb, W1, W2, bsum);

    void* args[] = { (void*)&bias, (void*)&vt1, (void*)&bsum, (void*)&u3, (void*)&pe,
                     (void*)&WB, (void*)&W4B, (void*)&gpart, (void*)&h, (void*)&c,
                     (void*)&spart, (void*)&state, (void*)&out };
    hipLaunchCooperativeKernel((void*)decode_kernel, dim3(256), dim3(256), args, 0, stream);
}

// Round 7
// 800.450 us; speedup vs baseline: 14.8237x; 1.0816x over previous
//
#include <hip/hip_runtime.h>
#include <math.h>

#define Bn   32
#define Sn   256
#define En   512
#define Hn   512
#define Wn   512
#define ENCn 1024
#define G4   2048
#define KTOT 1536

// ---------------- workspace layout (float offsets) ----------------
#define OFF_BSUM  0L            // [32][256][512]  4194304
#define OFF_U3    4194304L      // [32][256][512]  4194304  (pb overlays first 262144 during pe passes)
#define OFF_PE    8388608L      // [32][257][512]  4210688
#define OFF_WB    12599296L     // [32cb][256kq][64][4] 2097152
#define OFF_W4B   14696448L     // [8cb][128kq][64][4]   262144
#define OFF_GATES 14958592L     // [2kh][32][2048] 131072 (K-half partials)
#define OFF_H     15089664L     // [32][512]       16384
#define OFF_C     15106048L     // [2][32][512]    32768 (ping-pong by per-batch active-step parity)
#define OFF_SPART 15138816L     // [32][8][256]    65536
#define OFF_STATE 15204352L     // 8192 ints
// state ints:
//   packed64[b] : u64 at (u64*)state[768 + 16*b]   {epoch[0:16] | bond[16:32] | last[32:48]}
//   garr[b][64] : state[2560 + 64*b + (cb1*2+kh)]  P1 producer epoch flags (plain stores)
//   sflag[b][8] : state[4608 + 16*b + cb2]         P2 score-slice epoch flags

typedef unsigned long long u64t;

// ---------------- coherent (IF-level) access helpers ----------------
__device__ __forceinline__ float aload(const float* p) {
    return __hip_atomic_load(p, __ATOMIC_RELAXED, __HIP_MEMORY_SCOPE_AGENT);
}
__device__ __forceinline__ void astore(float* p, float v) {
    __hip_atomic_store(p, v, __ATOMIC_RELAXED, __HIP_MEMORY_SCOPE_AGENT);
}
__device__ __forceinline__ int aiload(const int* p) {
    return __hip_atomic_load(p, __ATOMIC_RELAXED, __HIP_MEMORY_SCOPE_AGENT);
}
__device__ __forceinline__ void aistore(int* p, int v) {
    __hip_atomic_store(p, v, __ATOMIC_RELAXED, __HIP_MEMORY_SCOPE_AGENT);
}
__device__ __forceinline__ u64t aload64(const u64t* p) {
    return __hip_atomic_load(p, __ATOMIC_RELAXED, __HIP_MEMORY_SCOPE_AGENT);
}
__device__ __forceinline__ void astore64(u64t* p, u64t v) {
    __hip_atomic_store(p, v, __ATOMIC_RELAXED, __HIP_MEMORY_SCOPE_AGENT);
}
__device__ __forceinline__ u64t pack2(float a, float b) {
    return (u64t)__float_as_uint(a) | ((u64t)__float_as_uint(b) << 32);
}
__device__ __forceinline__ float lo32(u64t v) { return __uint_as_float((unsigned)(v & 0xffffffffu)); }
__device__ __forceinline__ float hi32(u64t v) { return __uint_as_float((unsigned)(v >> 32)); }

// ---------------- init ----------------
__global__ void init_kernel(const float* __restrict__ hn0, float* __restrict__ h,
                            float* __restrict__ c, int* __restrict__ state)
{
    int i = blockIdx.x * blockDim.x + threadIdx.x;
    if (i < Bn * Hn) { h[i] = 0.0f; c[i] = hn0[i]; }
    if (i < 8192) state[i] = 0;
}

// ---------------- weight repack ----------------
__global__ void wtrans_kernel(const float* __restrict__ Wx, const float* __restrict__ Wh,
                              const float* __restrict__ W4, float* __restrict__ WB,
                              float* __restrict__ W4B)
{
    int idx = blockIdx.x * 256 + threadIdx.x;
    if (idx < 2097152) {
        const int cc = idx & 3, l = (idx >> 2) & 63, kq = (idx >> 8) & 255, cb = idx >> 16;
        const int k = 4 * kq + cc, j = cb * 64 + l;
        WB[idx] = (k < 512) ? Wx[(long)k * G4 + j] : Wh[(long)(k - 512) * G4 + j];
    }
    if (idx < 262144) {
        const int cc = idx & 3, l = (idx >> 2) & 63, kq = (idx >> 8) & 127, cb = idx >> 15;
        const int k = 4 * kq + cc, j = cb * 64 + l;
        W4B[idx] = W4[(long)k * Wn + j];
    }
}

// ---------------- pe: parallel prefix sums of inp over s ----------------
__global__ void pe1_kernel(const int* __restrict__ wid, const float* __restrict__ emb,
                           float* __restrict__ pb)
{
    const int b = blockIdx.x, blk = blockIdx.y;
    __shared__ int wids[16];
    if (threadIdx.x < 16) wids[threadIdx.x] = wid[b * Sn + blk * 16 + threadIdx.x];
    __syncthreads();
    float a0 = 0.f, a1 = 0.f;
    for (int s = 0; s < 16; ++s) {
        const float* r = emb + (long)wids[s] * En;
        a0 += r[threadIdx.x]; a1 += r[threadIdx.x + 256];
    }
    pb[((long)b * 16 + blk) * En + threadIdx.x] = a0;
    pb[((long)b * 16 + blk) * En + threadIdx.x + 256] = a1;
}

__global__ void pe2_kernel(const int* __restrict__ wid, const float* __restrict__ emb,
                           const float* __restrict__ pb, float* __restrict__ pe)
{
    const int b = blockIdx.x, blk = blockIdx.y;
    __shared__ int wids[16];
    if (threadIdx.x < 16) wids[threadIdx.x] = wid[b * Sn + blk * 16 + threadIdx.x];
    __syncthreads();
    float a0 = 0.f, a1 = 0.f;
    for (int j = 0; j < blk; ++j) {
        a0 += pb[((long)b * 16 + j) * En + threadIdx.x];
        a1 += pb[((long)b * 16 + j) * En + threadIdx.x + 256];
    }
    float* base = pe + (long)b * 257 * En;
    if (blk == 0) { base[threadIdx.x] = 0.f; base[threadIdx.x + 256] = 0.f; }
    for (int s = 0; s < 16; ++s) {
        const float* r = emb + (long)wids[s] * En;
        a0 += r[threadIdx.x]; a1 += r[threadIdx.x + 256];
        float* o = base + (long)(blk * 16 + s + 1) * En;
        o[threadIdx.x] = a0; o[threadIdx.x + 256] = a1;
    }
}

// ---------------- bsum = enc@W1 + emb[wid]@W2 ----------------
__global__ __launch_bounds__(256) void bsum_gemm(
    const float* __restrict__ enc, const int* __restrict__ wid,
    const float* __restrict__ emb, const float* __restrict__ W1,
    const float* __restrict__ W2, float* __restrict__ bsum)
{
    __shared__ float As[16][68];
    __shared__ float Bs[16][68];
    const int tid  = threadIdx.x;
    const int row0 = blockIdx.y * 64;
    const int col0 = blockIdx.x * 64;
    const int tm0  = (tid & 15) * 4;
    const int tn0  = (tid >> 4) * 4;
    const int la_r = tid >> 2;
    const int la_k = (tid & 3) * 4;
    const int lb_k = tid >> 4;
    const int lb_n = (tid & 15) * 4;

    float acc[4][4];
#pragma unroll
    for (int i = 0; i < 4; i++)
#pragma unroll
        for (int j = 0; j < 4; j++) acc[i][j] = 0.0f;

    for (int k0 = 0; k0 < KTOT; k0 += 16) {
        const int gr = row0 + la_r;
        float4 av;
        if (k0 < ENCn) {
            av = *(const float4*)&enc[(long)gr * ENCn + k0 + la_k];
        } else {
            const int wv = wid[gr];
            av = *(const float4*)&emb[(long)wv * En + (k0 - ENCn) + la_k];
        }
        As[la_k + 0][la_r] = av.x;
        As[la_k + 1][la_r] = av.y;
        As[la_k + 2][la_r] = av.z;
        As[la_k + 3][la_r] = av.w;
        float4 bv;
        if (k0 < ENCn) bv = *(const float4*)&W1[(long)(k0 + lb_k) * Wn + col0 + lb_n];
        else           bv = *(const float4*)&W2[(long)(k0 - ENCn + lb_k) * Wn + col0 + lb_n];
        *(float4*)&Bs[lb_k][lb_n] = bv;
        __syncthreads();
#pragma unroll
        for (int kk = 0; kk < 16; kk++) {
            float4 a = *(const float4*)&As[kk][tm0];
            float4 b = *(const float4*)&Bs[kk][tn0];
            acc[0][0] += a.x * b.x; acc[0][1] += a.x * b.y; acc[0][2] += a.x * b.z; acc[0][3] += a.x * b.w;
            acc[1][0] += a.y * b.x; acc[1][1] += a.y * b.y; acc[1][2] += a.y * b.z; acc[1][3] += a.y * b.w;
            acc[2][0] += a.z * b.x; acc[2][1] += a.z * b.y; acc[2][2] += a.z * b.z; acc[2][3] += a.z * b.w;
            acc[3][0] += a.w * b.x; acc[3][1] += a.w * b.y; acc[3][2] += a.w * b.z; acc[3][3] += a.w * b.w;
        }
        __syncthreads();
    }
#pragma unroll
    for (int i = 0; i < 4; i++) {
        float4 o = make_float4(acc[i][0], acc[i][1], acc[i][2], acc[i][3]);
        *(float4*)&bsum[(long)(row0 + tm0 + i) * Wn + col0 + tn0] = o;
    }
}

// ---------------- u3 = emb[wid]@W3 ----------------
__global__ __launch_bounds__(256) void u3_gemm(
    const int* __restrict__ wid, const float* __restrict__ emb,
    const float* __restrict__ W3, float* __restrict__ u3)
{
    __shared__ float As[16][68];
    __shared__ float Bs[16][68];
    const int tid  = threadIdx.x;
    const int row0 = blockIdx.y * 64;
    const int col0 = blockIdx.x * 64;
    const int tm0  = (tid & 15) * 4;
    const int tn0  = (tid >> 4) * 4;
    const int la_r = tid >> 2;
    const int la_k = (tid & 3) * 4;
    const int lb_k = tid >> 4;
    const int lb_n = (tid & 15) * 4;

    float acc[4][4];
#pragma unroll
    for (int i = 0; i < 4; i++)
#pragma unroll
        for (int j = 0; j < 4; j++) acc[i][j] = 0.0f;

    for (int k0 = 0; k0 < 512; k0 += 16) {
        const int gr = row0 + la_r;
        const int wv = wid[gr];
        float4 av = *(const float4*)&emb[(long)wv * En + k0 + la_k];
        As[la_k + 0][la_r] = av.x;
        As[la_k + 1][la_r] = av.y;
        As[la_k + 2][la_r] = av.z;
        As[la_k + 3][la_r] = av.w;
        *(float4*)&Bs[lb_k][lb_n] = *(const float4*)&W3[(long)(k0 + lb_k) * Wn + col0 + lb_n];
        __syncthreads();
#pragma unroll
        for (int kk = 0; kk < 16; kk++) {
            float4 a = *(const float4*)&As[kk][tm0];
            float4 b = *(const float4*)&Bs[kk][tn0];
            acc[0][0] += a.x * b.x; acc[0][1] += a.x * b.y; acc[0][2] += a.x * b.z; acc[0][3] += a.x * b.w;
            acc[1][0] += a.y * b.x; acc[1][1] += a.y * b.y; acc[1][2] += a.y * b.z; acc[1][3] += a.y * b.w;
            acc[2][0] += a.z * b.x; acc[2][1] += a.z * b.y; acc[2][2] += a.z * b.z; acc[2][3] += a.z * b.w;
            acc[3][0] += a.w * b.x; acc[3][1] += a.w * b.y; acc[3][2] += a.w * b.z; acc[3][3] += a.w * b.w;
        }
        __syncthreads();
    }
#pragma unroll
    for (int i = 0; i < 4; i++) {
        float4 o = make_float4(acc[i][0], acc[i][1], acc[i][2], acc[i][3]);
        *(float4*)&u3[(long)(row0 + tm0 + i) * Wn + col0 + tn0] = o;
    }
}

// ---------------- persistent decode: 256 WGs x 256 thr, flag dataflow, no RMW in steady state ----------------
__global__ __launch_bounds__(256) void decode_kernel(
    const float* __restrict__ bias, const float* __restrict__ vt1,
    const float* __restrict__ bsum, const float* __restrict__ u3,
    const float* __restrict__ pe,   const float* __restrict__ WB,
    const float* __restrict__ W4B,  float* __restrict__ gpart,
    float* __restrict__ hbuf, float* __restrict__ cbuf,
    float* __restrict__ spart,
    int* __restrict__ state, float* __restrict__ out)
{
    __shared__ __align__(16) float wlds[32768];   // 128 KB weight slice
    __shared__ __align__(16) float sx[4096];      // P1 stage / P2 work
    __shared__ __align__(16) float sred[2048];    // P1 cross-wave reduce
    __shared__ float s_svt[64];
    __shared__ float s_wv[4];
    __shared__ int   s_wi[4];
    __shared__ int   s_bd[8], s_ls[8];
    __shared__ int   s_exit;

    const int wg   = blockIdx.x;
    const int tid  = threadIdx.x;
    const int lane = tid & 63;
    const int wv   = tid >> 6;

    u64t* s64   = (u64t*)state;            // packed at s64[768 + 16*b]
    int*  garr  = state + 2560;            // [b][64]
    int*  sflag = state + 4608;            // [b][16] (8 used)

    const int cb1 = wg & 31;
    const int kh  = (wg >> 5) & 1;
    const int bg  = wg >> 6;          // 0..3, batches bg*8..bg*8+7
    const int b2  = wg >> 3;
    const int cb2 = wg & 7;
    const int bq2 = (wg >> 3) & 7;
    const float4* W4B4 = (const float4*)W4B;
    float4* wlds4 = (float4*)wlds;
    float4* sx4   = (float4*)sx;
    u64t* gp64 = (u64t*)gpart;
    u64t* h64  = (u64t*)hbuf;
    u64t* c64  = (u64t*)cbuf;
    const float2* pef2  = (const float2*)pe;
    const float2* bias2 = (const float2*)bias;

    // preload 128 KB weight slice
    {
        const float4* src = (const float4*)WB + ((long)cb1 * 256 + kh * 128) * 64;
        for (int i = tid; i < 8192; i += 256) wlds4[i] = src[i];
    }
    if (tid < 64) s_svt[tid] = vt1[cb2 * 64 + tid];

    int a_b = 0;   // active-step count of my P2 batch

    for (int t = 1; t <= Sn; ++t) {
        // ======== P1 wait: epochs of my 8 batches ========
        if (tid < 64) {
            const bool isb = tid < 8;
            const u64t* sp = s64 + 768 + 16 * (bg * 8 + (tid & 7));
            for (;;) {
                const u64t pk = isb ? aload64(sp) : 0ULL;
                const int ep = (int)(pk & 0xffffu);
                const int bd = (int)((pk >> 16) & 0xffffu);
                const bool ok = !isb || (ep >= t - 1) || (bd >= Sn);
                const bool dn = isb && (bd >= Sn);
                const u64t okb = __ballot(ok);
                const u64t dnb = __ballot(dn);
                if ((okb & 0xffULL) == 0xffULL) {
                    if (isb) { s_bd[tid] = bd; s_ls[tid] = (int)((pk >> 32) & 0xffffu); }
                    if (tid == 0) s_exit = ((dnb & 0xffULL) == 0xffULL);
                    break;
                }
                __builtin_amdgcn_s_sleep(1);
            }
        }
        __syncthreads();
        if (s_exit) break;     // whole group done -> this WG has no more work

        // ======== P1: stage 8 batches x 512 (x-half or h-half) ========
        for (int idx = tid; idx < 2048; idx += 256) {     // u64 granularity
            const int bq = idx >> 8, kp = idx & 255;
            const int b  = bg * 8 + bq;
            float v0 = 0.f, v1 = 0.f;
            if (s_bd[bq] < Sn) {
                if (kh == 0) {
                    const int bd = s_bd[bq], ls = s_ls[bq];
                    const float inv = 1.0f / (float)max(bd - ls, 1);
                    const float2 pa = pef2[((long)b * 257 + bd) * 256 + kp];
                    const float2 pb_ = pef2[((long)b * 257 + ls) * 256 + kp];
                    v0 = (pa.x - pb_.x) * inv;
                    v1 = (pa.y - pb_.y) * inv;
                } else {
                    const u64t hv = aload64(&h64[b * 256 + kp]);
                    v0 = lo32(hv); v1 = hi32(hv);
                }
            }
            sx[bq * 512 + 2 * kp]     = v0;
            sx[bq * 512 + 2 * kp + 1] = v1;
        }
        __syncthreads();
        // GEMV from LDS: wave wv owns K-chunk of 128; lane = col
        {
            float acc[8] = {0.f,0.f,0.f,0.f,0.f,0.f,0.f,0.f};
            const float4* wl = wlds4 + (wv * 32) * 64 + lane;
#pragma unroll 8
            for (int kq = 0; kq < 32; ++kq) {
                const float4 w = wl[kq * 64];
                const int kb = wv * 32 + kq;
#pragma unroll
                for (int bq = 0; bq < 8; ++bq) {
                    const float4 xv = sx4[bq * 128 + kb];
                    acc[bq] += w.x * xv.x + w.y * xv.y + w.z * xv.z + w.w * xv.w;
                }
            }
#pragma unroll
            for (int bq = 0; bq < 8; ++bq)
                sred[wv * 512 + bq * 64 + lane] = acc[bq];
        }
        __syncthreads();
        {
            const int bq = tid >> 5, cp = tid & 31;       // one u64 (2 cols) per thread
            if (s_bd[bq] < Sn) {
                const int c0 = 2 * cp, c1 = 2 * cp + 1;
                const float lo = sred[bq * 64 + c0] + sred[512 + bq * 64 + c0]
                               + sred[1024 + bq * 64 + c0] + sred[1536 + bq * 64 + c0];
                const float hi = sred[bq * 64 + c1] + sred[512 + bq * 64 + c1]
                               + sred[1024 + bq * 64 + c1] + sred[1536 + bq * 64 + c1];
                astore64(&gp64[(long)(kh * Bn + bg * 8 + bq) * 1024 + cb1 * 32 + cp], pack2(lo, hi));
            }
        }
        __syncthreads();   // drain gpart stores before flags
        if (tid < 8)
            aistore(&garr[64 * (bg * 8 + tid) + cb1 * 2 + kh], t);

        // ======== P2 ========
        const int bd = s_bd[bq2];
        if (bd < Sn) {
            ++a_b;
            // wait for all 64 gate slices of my batch
            if (tid < 64) {
                while (aiload(&garr[64 * b2 + tid]) < t) __builtin_amdgcn_s_sleep(1);
            }
            __syncthreads();
            // LSTM: one j-pair per thread (single pass)
            {
                const long base0 = (long)b2 * 1024;
                const long base1 = (long)(Bn + b2) * 1024;
                const u64t gi0 = aload64(&gp64[base0 + 0 * 256 + tid]);
                const u64t gf0 = aload64(&gp64[base0 + 1 * 256 + tid]);
                const u64t gg0 = aload64(&gp64[base0 + 2 * 256 + tid]);
                const u64t go0 = aload64(&gp64[base0 + 3 * 256 + tid]);
                const u64t gi1 = aload64(&gp64[base1 + 0 * 256 + tid]);
                const u64t gf1 = aload64(&gp64[base1 + 1 * 256 + tid]);
                const u64t gg1 = aload64(&gp64[base1 + 2 * 256 + tid]);
                const u64t go1 = aload64(&gp64[base1 + 3 * 256 + tid]);
                const u64t cv  = aload64(&c64[((a_b - 1) & 1) * 8192 + b2 * 256 + tid]);
                const float2 bi = bias2[0 * 256 + tid];
                const float2 bf = bias2[1 * 256 + tid];
                const float2 bg_ = bias2[2 * 256 + tid];
                const float2 bo = bias2[3 * 256 + tid];
                float h2a, h2b, cna, cnb;
                {
                    const float ig = lo32(gi0) + lo32(gi1) + bi.x;
                    const float fg = lo32(gf0) + lo32(gf1) + bf.x;
                    const float gg = lo32(gg0) + lo32(gg1) + bg_.x;
                    const float og = lo32(go0) + lo32(go1) + bo.x;
                    const float sf = 1.f / (1.f + expf(-fg));
                    const float si = 1.f / (1.f + expf(-ig));
                    const float so = 1.f / (1.f + expf(-og));
                    cna = sf * lo32(cv) + si * tanhf(gg);
                    h2a = so * tanhf(cna);
                }
                {
                    const float ig = hi32(gi0) + hi32(gi1) + bi.y;
                    const float fg = hi32(gf0) + hi32(gf1) + bf.y;
                    const float gg = hi32(gg0) + hi32(gg1) + bg_.y;
                    const float og = hi32(go0) + hi32(go1) + bo.y;
                    const float sf = 1.f / (1.f + expf(-fg));
                    const float si = 1.f / (1.f + expf(-ig));
                    const float so = 1.f / (1.f + expf(-og));
                    cnb = sf * hi32(cv) + si * tanhf(gg);
                    h2b = so * tanhf(cnb);
                }
                sx[2 * tid]     = h2a;
                sx[2 * tid + 1] = h2b;
                if (cb2 == 0) {
                    astore64(&h64[b2 * 256 + tid], pack2(h2a, h2b));
                    astore64(&c64[(a_b & 1) * 8192 + b2 * 256 + tid], pack2(cna, cnb));
                }
            }
            __syncthreads();
            // u4 slice (64 cols), wave-split K
            {
                float acc = 0.f;
                const float4* wrow = W4B4 + ((long)cb2 * 128 + wv * 32) * 64 + lane;
#pragma unroll 8
                for (int kq = 0; kq < 32; ++kq) {
                    const float4 w  = wrow[(long)kq * 64];
                    const float4 xv = sx4[wv * 32 + kq];
                    acc += w.x * xv.x + w.y * xv.y + w.z * xv.z + w.w * xv.w;
                }
                sx[512 + wv * 64 + lane] = acc;
            }
            __syncthreads();
            if (tid < 64) {
                const float* u3row = u3 + ((long)b2 * Sn + bd) * Wn + cb2 * 64;
                sx[768 + tid] = sx[512 + tid] + sx[576 + tid] + sx[640 + tid]
                              + sx[704 + tid] + u3row[tid];
            }
            __syncthreads();
            // partial scores: thread tid = row p
            if (tid >= bd) {
                const float* row = bsum + ((long)b2 * Sn + tid) * Wn + cb2 * 64;
                float a = 0.f;
#pragma unroll 8
                for (int i = 0; i < 64; ++i)
                    a += tanhf(row[i] + sx[768 + i]) * s_svt[i];
                astore(&spart[((long)b2 * 8 + cb2) * 256 + tid], a);
            }
            __syncthreads();                 // drain spart stores
            if (cb2 != 0) {
                if (tid == 0) aistore(&sflag[16 * b2 + cb2], a_b);
            } else {
                // fixed owner: poll 7 peer flags, then sum + argmax + publish
                if (tid >= 1 && tid < 8) {
                    while (aiload(&sflag[16 * b2 + tid]) < a_b) __builtin_amdgcn_s_sleep(1);
                }
                __syncthreads();
                float v = -3.402823e38f; int vi = Sn;
                if (tid >= bd) {
                    const float* sp = spart + (long)b2 * 8 * 256 + tid;
                    float s = 0.f;
#pragma unroll
                    for (int k = 0; k < 8; ++k) s += aload(&sp[k * 256]);
                    v = s; vi = tid;
                }
#pragma unroll
                for (int off = 32; off; off >>= 1) {
                    const float v2 = __shfl_xor(v, off, 64);
                    const int   i2 = __shfl_xor(vi, off, 64);
                    if (v2 > v || (v2 == v && i2 < vi)) { v = v2; vi = i2; }
                }
                if (lane == 0) { s_wv[wv] = v; s_wi[wv] = vi; }
                __syncthreads();
                if (tid == 0) {
                    float bv = s_wv[0]; int bi_ = s_wi[0];
#pragma unroll
                    for (int k = 1; k < 4; ++k)
                        if (s_wv[k] > bv || (s_wv[k] == bv && s_wi[k] < bi_)) { bv = s_wv[k]; bi_ = s_wi[k]; }
                    const int nb2 = (bi_ > bd) ? bi_ : bd + 1;
                    if (nb2 < Sn) out[nb2 * Bn + b2] = 1.0f;
                    const u64t pk =
                        (u64t)(unsigned)t |
                        ((u64t)(unsigned)nb2 << 16) |
                        ((u64t)(unsigned)bd  << 32);
                    astore64(&s64[768 + 16 * b2], pk);
                }
            }
        }
    }
}

extern "C" void kernel_launch(void* const* d_in, const int* in_sizes, int n_in,
                              void* d_out, int out_size, void* d_ws, size_t ws_size,
                              hipStream_t stream)
{
    const int*   wid  = (const int*)d_in[0];
    const float* enc  = (const float*)d_in[1];
    const float* hn0  = (const float*)d_in[2];
    const float* emb  = (const float*)d_in[3];
    // d_in[4] chunk_emb : unused (uniform score shift, argmax-invariant)
    const float* W1   = (const float*)d_in[5];
    const float* W2   = (const float*)d_in[6];
    const float* W3   = (const float*)d_in[7];
    const float* W4   = (const float*)d_in[8];
    const float* vt1  = (const float*)d_in[9];
    // d_in[10] vt2 : unused
    const float* Wx   = (const float*)d_in[11];
    const float* Wh   = (const float*)d_in[12];
    const float* bias = (const float*)d_in[13];

    float* ws    = (float*)d_ws;
    float* bsum  = ws + OFF_BSUM;
    float* u3    = ws + OFF_U3;
    float* pb    = ws + OFF_U3;       // overlay: used only before u3_gemm
    float* pe    = ws + OFF_PE;
    float* WB    = ws + OFF_WB;
    float* W4B   = ws + OFF_W4B;
    float* gpart = ws + OFF_GATES;
    float* h     = ws + OFF_H;
    float* c     = ws + OFF_C;
    float* spart = ws + OFF_SPART;
    int*   state = (int*)(ws + OFF_STATE);
    float* out   = (float*)d_out;

    hipMemsetAsync(d_out, 0, (size_t)Sn * Bn * sizeof(float), stream);
    hipLaunchKernelGGL(init_kernel, dim3(64), dim3(256), 0, stream, hn0, h, c, state);
    hipLaunchKernelGGL(wtrans_kernel, dim3(8192), dim3(256), 0, stream, Wx, Wh, W4, WB, W4B);
    hipLaunchKernelGGL(pe1_kernel, dim3(32, 16), dim3(256), 0, stream, wid, emb, pb);
    hipLaunchKernelGGL(pe2_kernel, dim3(32, 16), dim3(256), 0, stream, wid, emb, pb, pe);
    hipLaunchKernelGGL(u3_gemm, dim3(8, 128), dim3(256), 0, stream, wid, emb, W3, u3);
    hipLaunchKernelGGL(bsum_gemm, dim3(8, 128), dim3(256), 0, stream, enc, wid, emb, W1, W2, bsum);

    void* args[] = { (void*)&bias, (void*)&vt1, (void*)&bsum, (void*)&u3, (void*)&pe,
                     (void*)&WB, (void*)&W4B, (void*)&gpart, (void*)&h, (void*)&c,
                     (void*)&spart, (void*)&state, (void*)&out };
    hipLaunchCooperativeKernel((void*)decode_kernel, dim3(256), dim3(256), args, 0, stream);
}

// Round 9
// 796.061 us; speedup vs baseline: 14.9054x; 1.0055x over previous
//
#include <hip/hip_runtime.h>
#include <math.h>

#define Bn   32
#define Sn   256
#define En   512
#define Hn   512
#define Wn   512
#define ENCn 1024
#define G4   2048
#define KTOT 1536
#define BIGF 0x40000000

// ---------------- workspace layout (float offsets) ----------------
#define OFF_BSUM  0L            // [32][256][512]  4194304
#define OFF_U3    4194304L      // [32][256][512]  4194304  (pb overlays first 262144 during pe passes)
#define OFF_PE    8388608L      // [32][257][512]  4210688
#define OFF_WB    12599296L     // [32cb][256kq][64][4] 2097152
#define OFF_W4B   14696448L     // [8cb][128kq][64][4]   262144
#define OFF_GPX   14958592L     // [32][2048]       65536  (x-part gates, single buffer)
#define OFF_GPH   15024128L     // [2][32][2048]   131072  (h-part gates, t-parity)
#define OFF_H     15155200L     // [32][512]        16384
#define OFF_C     15171584L     // [2][32][512]     32768  (t-parity)
#define OFF_SPART 15204352L     // [2][32][8][256] 131072  (t-parity)
#define OFF_STATE 15335424L     // 8192 ints
// state ints:
//   s64[b]     : u64 at (u64*)state + 8*b          {epoch[0:16]|bond[16:32]|last[32:48]}
//   hflag[b]   : state[1024 + 16*b]                 (= t of published h_t; BIGF when done)
//   garr[b][64]: state[2048 + 64*b + cb1*2 + kh]    (= t)
//   sflag[b][8]: state[4096 + 16*b + cb2]           (= t)

typedef unsigned long long u64t;

// ---------------- coherent (IF-level) access helpers ----------------
__device__ __forceinline__ float aload(const float* p) {
    return __hip_atomic_load(p, __ATOMIC_RELAXED, __HIP_MEMORY_SCOPE_AGENT);
}
__device__ __forceinline__ void astore(float* p, float v) {
    __hip_atomic_store(p, v, __ATOMIC_RELAXED, __HIP_MEMORY_SCOPE_AGENT);
}
__device__ __forceinline__ int aiload(const int* p) {
    return __hip_atomic_load(p, __ATOMIC_RELAXED, __HIP_MEMORY_SCOPE_AGENT);
}
__device__ __forceinline__ void aistore(int* p, int v) {
    __hip_atomic_store(p, v, __ATOMIC_RELAXED, __HIP_MEMORY_SCOPE_AGENT);
}
__device__ __forceinline__ u64t aload64(const u64t* p) {
    return __hip_atomic_load(p, __ATOMIC_RELAXED, __HIP_MEMORY_SCOPE_AGENT);
}
__device__ __forceinline__ void astore64(u64t* p, u64t v) {
    __hip_atomic_store(p, v, __ATOMIC_RELAXED, __HIP_MEMORY_SCOPE_AGENT);
}
__device__ __forceinline__ u64t pack2(float a, float b) {
    return (u64t)__float_as_uint(a) | ((u64t)__float_as_uint(b) << 32);
}
__device__ __forceinline__ float lo32(u64t v) { return __uint_as_float((unsigned)(v & 0xffffffffu)); }
__device__ __forceinline__ float hi32(u64t v) { return __uint_as_float((unsigned)(v >> 32)); }

// ---------------- init ----------------
__global__ void init_kernel(const float* __restrict__ hn0, float* __restrict__ h,
                            float* __restrict__ c, int* __restrict__ state)
{
    int i = blockIdx.x * blockDim.x + threadIdx.x;
    if (i < Bn * Hn) { h[i] = 0.0f; c[i] = hn0[i]; }
    if (i < 8192) state[i] = 0;
}

// ---------------- weight repack ----------------
__global__ void wtrans_kernel(const float* __restrict__ Wx, const float* __restrict__ Wh,
                              const float* __restrict__ W4, float* __restrict__ WB,
                              float* __restrict__ W4B)
{
    int idx = blockIdx.x * 256 + threadIdx.x;
    if (idx < 2097152) {
        const int cc = idx & 3, l = (idx >> 2) & 63, kq = (idx >> 8) & 255, cb = idx >> 16;
        const int k = 4 * kq + cc, j = cb * 64 + l;
        WB[idx] = (k < 512) ? Wx[(long)k * G4 + j] : Wh[(long)(k - 512) * G4 + j];
    }
    if (idx < 262144) {
        const int cc = idx & 3, l = (idx >> 2) & 63, kq = (idx >> 8) & 127, cb = idx >> 15;
        const int k = 4 * kq + cc, j = cb * 64 + l;
        W4B[idx] = W4[(long)k * Wn + j];
    }
}

// ---------------- pe: parallel prefix sums of inp over s ----------------
__global__ void pe1_kernel(const int* __restrict__ wid, const float* __restrict__ emb,
                           float* __restrict__ pb)
{
    const int b = blockIdx.x, blk = blockIdx.y;
    __shared__ int wids[16];
    if (threadIdx.x < 16) wids[threadIdx.x] = wid[b * Sn + blk * 16 + threadIdx.x];
    __syncthreads();
    float a0 = 0.f, a1 = 0.f;
    for (int s = 0; s < 16; ++s) {
        const float* r = emb + (long)wids[s] * En;
        a0 += r[threadIdx.x]; a1 += r[threadIdx.x + 256];
    }
    pb[((long)b * 16 + blk) * En + threadIdx.x] = a0;
    pb[((long)b * 16 + blk) * En + threadIdx.x + 256] = a1;
}

__global__ void pe2_kernel(const int* __restrict__ wid, const float* __restrict__ emb,
                           const float* __restrict__ pb, float* __restrict__ pe)
{
    const int b = blockIdx.x, blk = blockIdx.y;
    __shared__ int wids[16];
    if (threadIdx.x < 16) wids[threadIdx.x] = wid[b * Sn + blk * 16 + threadIdx.x];
    __syncthreads();
    float a0 = 0.f, a1 = 0.f;
    for (int j = 0; j < blk; ++j) {
        a0 += pb[((long)b * 16 + j) * En + threadIdx.x];
        a1 += pb[((long)b * 16 + j) * En + threadIdx.x + 256];
    }
    float* base = pe + (long)b * 257 * En;
    if (blk == 0) { base[threadIdx.x] = 0.f; base[threadIdx.x + 256] = 0.f; }
    for (int s = 0; s < 16; ++s) {
        const float* r = emb + (long)wids[s] * En;
        a0 += r[threadIdx.x]; a1 += r[threadIdx.x + 256];
        float* o = base + (long)(blk * 16 + s + 1) * En;
        o[threadIdx.x] = a0; o[threadIdx.x + 256] = a1;
    }
}

// ---------------- bsum = enc@W1 + emb[wid]@W2 ----------------
__global__ __launch_bounds__(256) void bsum_gemm(
    const float* __restrict__ enc, const int* __restrict__ wid,
    const float* __restrict__ emb, const float* __restrict__ W1,
    const float* __restrict__ W2, float* __restrict__ bsum)
{
    __shared__ float As[16][68];
    __shared__ float Bs[16][68];
    const int tid  = threadIdx.x;
    const int row0 = blockIdx.y * 64;
    const int col0 = blockIdx.x * 64;
    const int tm0  = (tid & 15) * 4;
    const int tn0  = (tid >> 4) * 4;
    const int la_r = tid >> 2;
    const int la_k = (tid & 3) * 4;
    const int lb_k = tid >> 4;
    const int lb_n = (tid & 15) * 4;

    float acc[4][4];
#pragma unroll
    for (int i = 0; i < 4; i++)
#pragma unroll
        for (int j = 0; j < 4; j++) acc[i][j] = 0.0f;

    for (int k0 = 0; k0 < KTOT; k0 += 16) {
        const int gr = row0 + la_r;
        float4 av;
        if (k0 < ENCn) {
            av = *(const float4*)&enc[(long)gr * ENCn + k0 + la_k];
        } else {
            const int wv = wid[gr];
            av = *(const float4*)&emb[(long)wv * En + (k0 - ENCn) + la_k];
        }
        As[la_k + 0][la_r] = av.x;
        As[la_k + 1][la_r] = av.y;
        As[la_k + 2][la_r] = av.z;
        As[la_k + 3][la_r] = av.w;
        float4 bv;
        if (k0 < ENCn) bv = *(const float4*)&W1[(long)(k0 + lb_k) * Wn + col0 + lb_n];
        else           bv = *(const float4*)&W2[(long)(k0 - ENCn + lb_k) * Wn + col0 + lb_n];
        *(float4*)&Bs[lb_k][lb_n] = bv;
        __syncthreads();
#pragma unroll
        for (int kk = 0; kk < 16; kk++) {
            float4 a = *(const float4*)&As[kk][tm0];
            float4 b = *(const float4*)&Bs[kk][tn0];
            acc[0][0] += a.x * b.x; acc[0][1] += a.x * b.y; acc[0][2] += a.x * b.z; acc[0][3] += a.x * b.w;
            acc[1][0] += a.y * b.x; acc[1][1] += a.y * b.y; acc[1][2] += a.y * b.z; acc[1][3] += a.y * b.w;
            acc[2][0] += a.z * b.x; acc[2][1] += a.z * b.y; acc[2][2] += a.z * b.z; acc[2][3] += a.z * b.w;
            acc[3][0] += a.w * b.x; acc[3][1] += a.w * b.y; acc[3][2] += a.w * b.z; acc[3][3] += a.w * b.w;
        }
        __syncthreads();
    }
#pragma unroll
    for (int i = 0; i < 4; i++) {
        float4 o = make_float4(acc[i][0], acc[i][1], acc[i][2], acc[i][3]);
        *(float4*)&bsum[(long)(row0 + tm0 + i) * Wn + col0 + tn0] = o;
    }
}

// ---------------- u3 = emb[wid]@W3 ----------------
__global__ __launch_bounds__(256) void u3_gemm(
    const int* __restrict__ wid, const float* __restrict__ emb,
    const float* __restrict__ W3, float* __restrict__ u3)
{
    __shared__ float As[16][68];
    __shared__ float Bs[16][68];
    const int tid  = threadIdx.x;
    const int row0 = blockIdx.y * 64;
    const int col0 = blockIdx.x * 64;
    const int tm0  = (tid & 15) * 4;
    const int tn0  = (tid >> 4) * 4;
    const int la_r = tid >> 2;
    const int la_k = (tid & 3) * 4;
    const int lb_k = tid >> 4;
    const int lb_n = (tid & 15) * 4;

    float acc[4][4];
#pragma unroll
    for (int i = 0; i < 4; i++)
#pragma unroll
        for (int j = 0; j < 4; j++) acc[i][j] = 0.0f;

    for (int k0 = 0; k0 < 512; k0 += 16) {
        const int gr = row0 + la_r;
        const int wv = wid[gr];
        float4 av = *(const float4*)&emb[(long)wv * En + k0 + la_k];
        As[la_k + 0][la_r] = av.x;
        As[la_k + 1][la_r] = av.y;
        As[la_k + 2][la_r] = av.z;
        As[la_k + 3][la_r] = av.w;
        *(float4*)&Bs[lb_k][lb_n] = *(const float4*)&W3[(long)(k0 + lb_k) * Wn + col0 + lb_n];
        __syncthreads();
#pragma unroll
        for (int kk = 0; kk < 16; kk++) {
            float4 a = *(const float4*)&As[kk][tm0];
            float4 b = *(const float4*)&Bs[kk][tn0];
            acc[0][0] += a.x * b.x; acc[0][1] += a.x * b.y; acc[0][2] += a.x * b.z; acc[0][3] += a.x * b.w;
            acc[1][0] += a.y * b.x; acc[1][1] += a.y * b.y; acc[1][2] += a.y * b.z; acc[1][3] += a.y * b.w;
            acc[2][0] += a.z * b.x; acc[2][1] += a.z * b.y; acc[2][2] += a.z * b.z; acc[2][3] += a.z * b.w;
            acc[3][0] += a.w * b.x; acc[3][1] += a.w * b.y; acc[3][2] += a.w * b.z; acc[3][3] += a.w * b.w;
        }
        __syncthreads();
    }
#pragma unroll
    for (int i = 0; i < 4; i++) {
        float4 o = make_float4(acc[i][0], acc[i][1], acc[i][2], acc[i][3]);
        *(float4*)&u3[(long)(row0 + tm0 + i) * Wn + col0 + tn0] = o;
    }
}

// ---------------- persistent decode: event-driven dataflow, h-GEMV off critical path ----------------
// Roles per WG (wg 0..255):
//   P1: (cb1 = wg&31 [64 cols of 2048], kh = (wg>>5)&1, bg = wg>>6 [8 batches]).
//       kh==0 (x-part, K=x[512]): triggered by s64 epoch >= t-1.
//       kh==1 (h-part, K=h[512]): triggered by hflag >= t-1 (set mid-P2, BEFORE the decision).
//   P2: (b2 = wg>>3, cb2 = wg&7): poll 64 garr; LSTM; owner publishes h64+hflag EARLY;
//       u4+scores -> spart(parity); all 8 WGs redundantly sum+argmax (local decision);
//       owner publishes s64 (for P1-x) and out.
__global__ __launch_bounds__(256) void decode_kernel(
    const float* __restrict__ bias, const float* __restrict__ vt1,
    const float* __restrict__ bsum, const float* __restrict__ u3,
    const float* __restrict__ pe,   const float* __restrict__ WB,
    const float* __restrict__ W4B,  float* __restrict__ gpx,
    float* __restrict__ gph,
    float* __restrict__ hbuf, float* __restrict__ cbuf,
    float* __restrict__ spart,
    int* __restrict__ state, float* __restrict__ out)
{
    __shared__ __align__(16) float wlds[32768];   // 128 KB weight slice
    __shared__ __align__(16) float sx[4096];      // P1 stage / P2 work
    __shared__ __align__(16) float sred[2048];    // P1 cross-wave reduce
    __shared__ float s_svt[64];
    __shared__ float s_wv[4];
    __shared__ int   s_wi[4];
    __shared__ int   s_bd[8], s_ls[8];
    __shared__ int   s_p1done;

    const int wg   = blockIdx.x;
    const int tid  = threadIdx.x;
    const int lane = tid & 63;
    const int wv   = tid >> 6;

    u64t* s64g  = (u64t*)state;            // s64g[8*b]
    int*  hflag = state + 1024;            // hflag[16*b]
    int*  garr  = state + 2048;            // [b][64]
    int*  sflag = state + 4096;            // [b][16] (8 used)

    const int cb1 = wg & 31;
    const int kh  = (wg >> 5) & 1;
    const int bg  = wg >> 6;          // 0..3, batches bg*8..bg*8+7
    const int b2  = wg >> 3;
    const int cb2 = wg & 7;
    const float4* W4B4 = (const float4*)W4B;
    float4* wlds4 = (float4*)wlds;
    float4* sx4   = (float4*)sx;
    u64t* gpx64 = (u64t*)gpx;
    u64t* gph64 = (u64t*)gph;
    u64t* h64   = (u64t*)hbuf;
    u64t* c64   = (u64t*)cbuf;
    const float2* pef2  = (const float2*)pe;
    const float2* bias2 = (const float2*)bias;

    // preload 128 KB weight slice (kh=0 -> Wx-part rows of WB; kh=1 -> Wh-part)
    {
        const float4* src = (const float4*)WB + ((long)cb1 * 256 + kh * 128) * 64;
        for (int i = tid; i < 8192; i += 256) wlds4[i] = src[i];
    }
    if (tid < 64) s_svt[tid] = vt1[cb2 * 64 + tid];

    bool p1done = false, p2done = false;
    int my_bd = 0, my_ls = 0;

    for (int t = 1; t <= Sn; ++t) {
        if (p1done && p2done) break;

        // ======== P1 ========
        if (!p1done) {
            if (kh == 0) {
                if (tid < 64) {
                    const bool isb = tid < 8;
                    const u64t* sp = s64g + 8 * (bg * 8 + (tid & 7));
                    for (;;) {
                        const u64t pk = isb ? aload64(sp) : 0ULL;
                        const int ep = (int)(pk & 0xffffu);
                        const int bd = (int)((pk >> 16) & 0xffffu);
                        const bool ok = !isb || (ep >= t - 1) || (bd >= Sn);
                        const u64t okb = __ballot(ok);
                        const u64t dnb = __ballot(isb && (bd >= Sn));
                        if ((okb & 0xffULL) == 0xffULL) {
                            if (isb) { s_bd[tid] = bd; s_ls[tid] = (int)((pk >> 32) & 0xffffu); }
                            if (tid == 0) s_p1done = ((dnb & 0xffULL) == 0xffULL);
                            break;
                        }
                        __builtin_amdgcn_s_sleep(1);
                    }
                }
            } else {
                if (tid < 64) {
                    const bool isb = tid < 8;
                    const int* hp = hflag + 16 * (bg * 8 + (tid & 7));
                    for (;;) {
                        const int hf = isb ? aiload(hp) : 0x7ffffff0;
                        const bool ok = (hf >= t - 1);
                        const u64t okb = __ballot(ok);
                        const u64t dnb = __ballot(isb && (hf >= BIGF));
                        if ((okb & 0xffULL) == 0xffULL) {
                            if (isb) { s_bd[tid] = (hf >= BIGF) ? Sn : 0; s_ls[tid] = 0; }
                            if (tid == 0) s_p1done = ((dnb & 0xffULL) == 0xffULL);
                            break;
                        }
                        __builtin_amdgcn_s_sleep(1);
                    }
                }
            }
            __syncthreads();
            if (s_p1done) p1done = true;
            if (!p1done) {
                // stage 8 batches x 512 (x via pe-diff, or h via h64)
                for (int idx = tid; idx < 2048; idx += 256) {     // u64 granularity
                    const int bq = idx >> 8, kp = idx & 255;
                    const int b  = bg * 8 + bq;
                    float v0 = 0.f, v1 = 0.f;
                    if (s_bd[bq] < Sn) {
                        if (kh == 0) {
                            const int bd = s_bd[bq], ls = s_ls[bq];
                            const float inv = 1.0f / (float)max(bd - ls, 1);
                            const float2 pa  = pef2[((long)b * 257 + bd) * 256 + kp];
                            const float2 pb_ = pef2[((long)b * 257 + ls) * 256 + kp];
                            v0 = (pa.x - pb_.x) * inv;
                            v1 = (pa.y - pb_.y) * inv;
                        } else {
                            const u64t hv = aload64(&h64[b * 256 + kp]);
                            v0 = lo32(hv); v1 = hi32(hv);
                        }
                    }
                    sx[bq * 512 + 2 * kp]     = v0;
                    sx[bq * 512 + 2 * kp + 1] = v1;
                }
                __syncthreads();
                // GEMV from LDS: wave wv owns K-chunk of 128; lane = col
                {
                    float acc[8] = {0.f,0.f,0.f,0.f,0.f,0.f,0.f,0.f};
                    const float4* wl = wlds4 + (wv * 32) * 64 + lane;
#pragma unroll 8
                    for (int kq = 0; kq < 32; ++kq) {
                        const float4 w = wl[kq * 64];
                        const int kb = wv * 32 + kq;
#pragma unroll
                        for (int bq = 0; bq < 8; ++bq) {
                            const float4 xv = sx4[bq * 128 + kb];
                            acc[bq] += w.x * xv.x + w.y * xv.y + w.z * xv.z + w.w * xv.w;
                        }
                    }
#pragma unroll
                    for (int bq = 0; bq < 8; ++bq)
                        sred[wv * 512 + bq * 64 + lane] = acc[bq];
                }
                __syncthreads();
                {
                    const int bq = tid >> 5, cp = tid & 31;       // one u64 (2 cols) per thread
                    if (s_bd[bq] < Sn) {
                        const int c0 = 2 * cp, c1 = 2 * cp + 1;
                        const float lo = sred[bq * 64 + c0] + sred[512 + bq * 64 + c0]
                                       + sred[1024 + bq * 64 + c0] + sred[1536 + bq * 64 + c0];
                        const float hi = sred[bq * 64 + c1] + sred[512 + bq * 64 + c1]
                                       + sred[1024 + bq * 64 + c1] + sred[1536 + bq * 64 + c1];
                        if (kh == 0)
                            astore64(&gpx64[(long)(bg * 8 + bq) * 1024 + cb1 * 32 + cp], pack2(lo, hi));
                        else
                            astore64(&gph64[(long)(t & 1) * 32768 + (long)(bg * 8 + bq) * 1024 + cb1 * 32 + cp], pack2(lo, hi));
                    }
                }
                __syncthreads();   // drain gpart stores before flags
                if (tid < 8)
                    aistore(&garr[64 * (bg * 8 + tid) + cb1 * 2 + kh], t);
            }
        }

        // ======== P2 ========
        if (!p2done) {
            const int bd = my_bd;
            // prefetch u3 row (hides IF latency under garr poll)
            float u3v = 0.f;
            if (tid < 64) u3v = aload(&u3[((long)b2 * Sn + bd) * Wn + cb2 * 64 + tid]);
            // wait for all 64 gate slices of my batch
            if (tid < 64) {
                const int* gp = garr + 64 * b2 + tid;
                while (aiload(gp) < t) __builtin_amdgcn_s_sleep(1);
            }
            __syncthreads();
            // LSTM: one j-pair per thread
            {
                const long bx = (long)b2 * 1024;
                const long bh = (long)(t & 1) * 32768 + (long)b2 * 1024;
                const u64t gi0 = aload64(&gpx64[bx + 0 * 256 + tid]);
                const u64t gf0 = aload64(&gpx64[bx + 1 * 256 + tid]);
                const u64t gg0 = aload64(&gpx64[bx + 2 * 256 + tid]);
                const u64t go0 = aload64(&gpx64[bx + 3 * 256 + tid]);
                const u64t gi1 = aload64(&gph64[bh + 0 * 256 + tid]);
                const u64t gf1 = aload64(&gph64[bh + 1 * 256 + tid]);
                const u64t gg1 = aload64(&gph64[bh + 2 * 256 + tid]);
                const u64t go1 = aload64(&gph64[bh + 3 * 256 + tid]);
                const u64t cv  = aload64(&c64[(long)((t - 1) & 1) * 8192 + b2 * 256 + tid]);
                const float2 bi  = bias2[0 * 256 + tid];
                const float2 bf  = bias2[1 * 256 + tid];
                const float2 bg_ = bias2[2 * 256 + tid];
                const float2 bo  = bias2[3 * 256 + tid];
                float h2a, h2b, cna, cnb;
                {
                    const float ig = lo32(gi0) + lo32(gi1) + bi.x;
                    const float fg = lo32(gf0) + lo32(gf1) + bf.x;
                    const float gg = lo32(gg0) + lo32(gg1) + bg_.x;
                    const float og = lo32(go0) + lo32(go1) + bo.x;
                    const float sf = 1.f / (1.f + expf(-fg));
                    const float si = 1.f / (1.f + expf(-ig));
                    const float so = 1.f / (1.f + expf(-og));
                    cna = sf * lo32(cv) + si * tanhf(gg);
                    h2a = so * tanhf(cna);
                }
                {
                    const float ig = hi32(gi0) + hi32(gi1) + bi.y;
                    const float fg = hi32(gf0) + hi32(gf1) + bf.y;
                    const float gg = hi32(gg0) + hi32(gg1) + bg_.y;
                    const float og = hi32(go0) + hi32(go1) + bo.y;
                    const float sf = 1.f / (1.f + expf(-fg));
                    const float si = 1.f / (1.f + expf(-ig));
                    const float so = 1.f / (1.f + expf(-og));
                    cnb = sf * hi32(cv) + si * tanhf(gg);
                    h2b = so * tanhf(cnb);
                }
                sx[2 * tid]     = h2a;
                sx[2 * tid + 1] = h2b;
                if (cb2 == 0) {
                    astore64(&h64[b2 * 256 + tid], pack2(h2a, h2b));
                    astore64(&c64[(long)(t & 1) * 8192 + b2 * 256 + tid], pack2(cna, cnb));
                }
            }
            __syncthreads();
            // publish h EARLY -> unblocks P1-h for step t+1 while we do u4/scores
            if (cb2 == 0 && tid == 0) aistore(&hflag[16 * b2], t);
            // u4 slice (64 cols), wave-split K
            {
                float acc = 0.f;
                const float4* wrow = W4B4 + ((long)cb2 * 128 + wv * 32) * 64 + lane;
#pragma unroll 8
                for (int kq = 0; kq < 32; ++kq) {
                    const float4 w  = wrow[(long)kq * 64];
                    const float4 xv = sx4[wv * 32 + kq];
                    acc += w.x * xv.x + w.y * xv.y + w.z * xv.z + w.w * xv.w;
                }
                sx[512 + wv * 64 + lane] = acc;
            }
            __syncthreads();
            if (tid < 64) {
                sx[768 + tid] = sx[512 + tid] + sx[576 + tid] + sx[640 + tid]
                              + sx[704 + tid] + u3v;
            }
            __syncthreads();
            // partial scores: thread tid = row p
            if (tid >= bd) {
                const float* row = bsum + ((long)b2 * Sn + tid) * Wn + cb2 * 64;
                float a = 0.f;
#pragma unroll 8
                for (int i = 0; i < 64; ++i)
                    a += tanhf(row[i] + sx[768 + i]) * s_svt[i];
                astore(&spart[(long)(t & 1) * 65536 + (long)b2 * 2048 + cb2 * 256 + tid], a);
            }
            __syncthreads();                 // drain spart stores
            if (tid == 0) aistore(&sflag[16 * b2 + cb2], t);
            // all 8 WGs: poll peers, then REDUNDANT sum + argmax (local decision)
            if (tid < 8) {
                const int* sp = sflag + 16 * b2 + tid;
                while (aiload(sp) < t) __builtin_amdgcn_s_sleep(1);
            }
            __syncthreads();
            float v = -3.402823e38f; int vi = Sn;
            if (tid >= bd) {
                const float* sp = spart + (long)(t & 1) * 65536 + (long)b2 * 2048 + tid;
                float s = 0.f;
#pragma unroll
                for (int k = 0; k < 8; ++k) s += aload(&sp[k * 256]);
                v = s; vi = tid;
            }
#pragma unroll
            for (int off = 32; off; off >>= 1) {
                const float v2 = __shfl_xor(v, off, 64);
                const int   i2 = __shfl_xor(vi, off, 64);
                if (v2 > v || (v2 == v && i2 < vi)) { v = v2; vi = i2; }
            }
            if (lane == 0) { s_wv[wv] = v; s_wi[wv] = vi; }
            __syncthreads();
            {
                float bv = s_wv[0]; int bi_ = s_wi[0];
#pragma unroll
                for (int k = 1; k < 4; ++k)
                    if (s_wv[k] > bv || (s_wv[k] == bv && s_wi[k] < bi_)) { bv = s_wv[k]; bi_ = s_wi[k]; }
                const int nb2 = (bi_ > bd) ? bi_ : bd + 1;
                my_ls = bd; my_bd = nb2;
                if (cb2 == 0 && tid == 0) {
                    if (nb2 < Sn) out[nb2 * Bn + b2] = 1.0f;
                    const u64t pk = (u64t)(unsigned)t |
                                    ((u64t)(unsigned)nb2 << 16) |
                                    ((u64t)(unsigned)bd  << 32);
                    astore64(&s64g[8 * b2], pk);
                    if (nb2 >= Sn) aistore(&hflag[16 * b2], BIGF);
                }
                if (nb2 >= Sn) p2done = true;
            }
            __syncthreads();
        }
    }
}

extern "C" void kernel_launch(void* const* d_in, const int* in_sizes, int n_in,
                              void* d_out, int out_size, void* d_ws, size_t ws_size,
                              hipStream_t stream)
{
    const int*   wid  = (const int*)d_in[0];
    const float* enc  = (const float*)d_in[1];
    const float* hn0  = (const float*)d_in[2];
    const float* emb  = (const float*)d_in[3];
    // d_in[4] chunk_emb : unused (uniform score shift, argmax-invariant)
    const float* W1   = (const float*)d_in[5];
    const float* W2   = (const float*)d_in[6];
    const float* W3   = (const float*)d_in[7];
    const float* W4   = (const float*)d_in[8];
    const float* vt1  = (const float*)d_in[9];
    // d_in[10] vt2 : unused
    const float* Wx   = (const float*)d_in[11];
    const float* Wh   = (const float*)d_in[12];
    const float* bias = (const float*)d_in[13];

    float* ws    = (float*)d_ws;
    float* bsum  = ws + OFF_BSUM;
    float* u3    = ws + OFF_U3;
    float* pb    = ws + OFF_U3;       // overlay: used only before u3_gemm
    float* pe    = ws + OFF_PE;
    float* WB    = ws + OFF_WB;
    float* W4B   = ws + OFF_W4B;
    float* gpx   = ws + OFF_GPX;
    float* gph   = ws + OFF_GPH;
    float* h     = ws + OFF_H;
    float* c     = ws + OFF_C;
    float* spart = ws + OFF_SPART;
    int*   state = (int*)(ws + OFF_STATE);
    float* out   = (float*)d_out;

    (void)hipMemsetAsync(d_out, 0, (size_t)Sn * Bn * sizeof(float), stream);
    hipLaunchKernelGGL(init_kernel, dim3(64), dim3(256), 0, stream, hn0, h, c, state);
    hipLaunchKernelGGL(wtrans_kernel, dim3(8192), dim3(256), 0, stream, Wx, Wh, W4, WB, W4B);
    hipLaunchKernelGGL(pe1_kernel, dim3(32, 16), dim3(256), 0, stream, wid, emb, pb);
    hipLaunchKernelGGL(pe2_kernel, dim3(32, 16), dim3(256), 0, stream, wid, emb, pb, pe);
    hipLaunchKernelGGL(u3_gemm, dim3(8, 128), dim3(256), 0, stream, wid, emb, W3, u3);
    hipLaunchKernelGGL(bsum_gemm, dim3(8, 128), dim3(256), 0, stream, enc, wid, emb, W1, W2, bsum);

    void* args[] = { (void*)&bias, (void*)&vt1, (void*)&bsum, (void*)&u3, (void*)&pe,
                     (void*)&WB, (void*)&W4B, (void*)&gpx, (void*)&gph, (void*)&h, (void*)&c,
                     (void*)&spart, (void*)&state, (void*)&out };
    (void)hipLaunchCooperativeKernel((void*)decode_kernel, dim3(256), dim3(256), args, 0, stream);
}